// Round 7
// baseline (181.161 us; speedup 1.0000x reference)
//
#include <hip/hip_runtime.h>
#include <math.h>

// ExpertGating: h=relu(hs@W1+b1); logits=h@W2+b2; softmax; top-2; combine.
// R7: combine fused into GEMM as a tail-reduction. Each GEMM block writes its
// logit partials, fences, bumps a per-rb counter; the 8th arriver combines the
// 128 tokens of that rb (softmax/top2/gather/write) -- overlapping the
// memory-bound combine under the compute-bound GEMM. Counters zeroed in-graph
// via hipMemsetAsync. GEMM loop + logits epilogue identical to R6 (verified).

#define H_DIM 1024
#define E_NUM 8

typedef __attribute__((ext_vector_type(8))) short s16x8;
typedef __attribute__((ext_vector_type(8))) unsigned short u16x8;
typedef __attribute__((ext_vector_type(4))) float f32x4;

__device__ __forceinline__ unsigned short f2bf(float x) {
    unsigned int u = __float_as_uint(x);
    unsigned int r = (u + 0x7FFFu + ((u >> 16) & 1u)) >> 16;
    return (unsigned short)r;
}
__device__ __forceinline__ float bf2f(unsigned short b) {
    return __uint_as_float(((unsigned int)b) << 16);
}
__device__ __forceinline__ void gload_lds16(const void* g, void* lds) {
    __builtin_amdgcn_global_load_lds(
        (const __attribute__((address_space(1))) void*)g,
        (__attribute__((address_space(3))) void*)lds, 16, 0, 0);
}

// ---------------- fused prep: hs and W1 -> swizzled hi/lo bf16 images --------
__global__ __launch_bounds__(256) void prep_fused_kernel(
    const float* __restrict__ A, const float* __restrict__ W,
    char* __restrict__ Aimg, char* __restrict__ Bimg)
{
    if (blockIdx.x < 4096) {
        int t = blockIdx.x * 256 + threadIdx.x;   // 8192 rows x 128 octets
        int m = t >> 7;
        int k = (t & 127) << 3;
        const float* src = A + ((size_t)m << 10) + k;
        float4 v0 = *reinterpret_cast<const float4*>(src);
        float4 v1 = *reinterpret_cast<const float4*>(src + 4);
        float xs[8] = {v0.x, v0.y, v0.z, v0.w, v1.x, v1.y, v1.z, v1.w};
        u16x8 hv, lv;
        #pragma unroll
        for (int j = 0; j < 8; ++j) {
            unsigned short h = f2bf(xs[j]);
            hv[j] = h;
            lv[j] = f2bf(xs[j] - bf2f(h));
        }
        int rb = m >> 7, mr = m & 127, kt = k >> 5, s = (k >> 3) & 3;
        char* base = Aimg + (((size_t)(rb * 32 + kt)) << 14) + mr * 128;
        *reinterpret_cast<u16x8*>(base + ((s ^ (mr & 7)) << 4)) = hv;
        *reinterpret_cast<u16x8*>(base + (((s + 4) ^ (mr & 7)) << 4)) = lv;
    } else {
        int t = (blockIdx.x - 4096) * 256 + threadIdx.x;  // 1024 cols x 128 octets
        int n = t & 1023;
        int k = (t >> 10) << 3;
        u16x8 hv, lv;
        #pragma unroll
        for (int j = 0; j < 8; ++j) {
            float x = W[((size_t)(k + j) << 10) + n];
            unsigned short h = f2bf(x);
            hv[j] = h;
            lv[j] = f2bf(x - bf2f(h));
        }
        int cb = n >> 7, nr = n & 127, kt = k >> 5, s = (k >> 3) & 3;
        char* base = Bimg + (((size_t)(cb * 32 + kt)) << 14) + nr * 128;
        *reinterpret_cast<u16x8*>(base + ((s ^ (nr & 7)) << 4)) = hv;
        *reinterpret_cast<u16x8*>(base + (((s + 4) ^ (nr & 7)) << 4)) = lv;
    }
}

// ---------------- GEMM1 + fused router logits + fused tail combine ----------
// LDS map: [0,16384)=As / h_hi[128][64]; [16384,32768)=Bs / h_lo[128][64];
//          [32768,39296)=w2t 24 rows x 272B; [39296,39300)=last-block flag
#define MFMA_B16 __builtin_amdgcn_mfma_f32_16x16x32_bf16
#define W2T_OFS 32768
#define W2T_PITCH 272
#define FLAG_OFS 39296

__global__ __launch_bounds__(256, 3) void gemm1_logits_kernel(
    const char* __restrict__ Aimg, const char* __restrict__ Bimg,
    const float* __restrict__ bias, const float* __restrict__ W2,
    float* __restrict__ Plog, const float* __restrict__ b2,
    const float* __restrict__ EO, float* __restrict__ Out,
    int* __restrict__ Cnt)
{
    __shared__ char smem[39304];

    int bid = blockIdx.x;
    int swz = (bid & 7) * 64 + (bid >> 3);   // bijective, 512 % 8 == 0
    int rb = swz >> 3;          // 0..63
    int cb = swz & 7;           // 0..7

    int tid = threadIdx.x;
    int lane = tid & 63;
    int wave = tid >> 6;
    int wm = (wave >> 1) * 64;
    int wn = (wave & 1) * 64;
    int l15 = lane & 15, l4 = lane >> 4;

    // ---- w2t: zero, then fill hi/lo bf16 of W2 slice (transposed) ----
    const int col0g = cb * 128;
    for (int i = tid; i < 1632; i += 256)
        *reinterpret_cast<float*>(smem + W2T_OFS + i * 4) = 0.f;
    __syncthreads();
    {
        int e = tid & 7, c4 = tid >> 3;   // c4: 0..31
        #pragma unroll
        for (int j = 0; j < 4; ++j) {
            int col = c4 * 4 + j;
            float w = W2[(size_t)(col0g + col) * E_NUM + e];
            unsigned short wh = f2bf(w);
            unsigned short wl = f2bf(w - bf2f(wh));
            *reinterpret_cast<unsigned short*>(smem + W2T_OFS + e * W2T_PITCH + col * 2) = wh;
            *reinterpret_cast<unsigned short*>(smem + W2T_OFS + (e + 8) * W2T_PITCH + col * 2) = wl;
        }
    }
    __syncthreads();

    // fragment LDS offsets (swizzle baked in), constant across K-tiles
    int aoff_h[4], aoff_l[4], boff_h[4], boff_l[4];
    #pragma unroll
    for (int f = 0; f < 4; ++f) {
        int ar = wm + f * 16 + l15;
        aoff_h[f] = ar * 128 + ((l4 ^ (ar & 7)) << 4);
        aoff_l[f] = ar * 128 + (((l4 + 4) ^ (ar & 7)) << 4);
        int br = wn + f * 16 + l15;
        boff_h[f] = 16384 + br * 128 + ((l4 ^ (br & 7)) << 4);
        boff_l[f] = 16384 + br * 128 + (((l4 + 4) ^ (br & 7)) << 4);
    }

    const char* abase = Aimg + (size_t)rb * (32 * 16384);
    const char* bbase = Bimg + (size_t)cb * (32 * 16384);

    f32x4 acc[4][4];
    #pragma unroll
    for (int i = 0; i < 4; ++i)
        #pragma unroll
        for (int j = 0; j < 4; ++j)
            acc[i][j] = (f32x4){0.f, 0.f, 0.f, 0.f};

    for (int kt = 0; kt < 32; ++kt) {
        const char* ga = abase + (kt << 14);
        const char* gb = bbase + (kt << 14);
        int toff = tid << 4;
        #pragma unroll
        for (int r = 0; r < 4; ++r) {
            gload_lds16(ga + (r << 12) + toff, smem + (r << 12) + toff);
            gload_lds16(gb + (r << 12) + toff, smem + 16384 + (r << 12) + toff);
        }
        __syncthreads();

        s16x8 ah[4], al[4], bh[4], bl[4];
        #pragma unroll
        for (int f = 0; f < 4; ++f) {
            ah[f] = *reinterpret_cast<const s16x8*>(smem + aoff_h[f]);
            al[f] = *reinterpret_cast<const s16x8*>(smem + aoff_l[f]);
            bh[f] = *reinterpret_cast<const s16x8*>(smem + boff_h[f]);
            bl[f] = *reinterpret_cast<const s16x8*>(smem + boff_l[f]);
        }
        #pragma unroll
        for (int m = 0; m < 4; ++m)
            #pragma unroll
            for (int n = 0; n < 4; ++n)
                acc[m][n] = MFMA_B16(ah[m], bh[n], acc[m][n], 0, 0, 0);
        #pragma unroll
        for (int m = 0; m < 4; ++m)
            #pragma unroll
            for (int n = 0; n < 4; ++n)
                acc[m][n] = MFMA_B16(ah[m], bl[n], acc[m][n], 0, 0, 0);
        #pragma unroll
        for (int m = 0; m < 4; ++m)
            #pragma unroll
            for (int n = 0; n < 4; ++n)
                acc[m][n] = MFMA_B16(al[m], bh[n], acc[m][n], 0, 0, 0);
        __syncthreads();
    }

    // ---- fused epilogue: P[row][e] = relu(acc + b1) @ W2slice, 3-pass split ----
    float bcol[4];
    #pragma unroll
    for (int fn = 0; fn < 4; ++fn) bcol[fn] = bias[col0g + wn + fn * 16 + l15];

    f32x4 plog[2];
    plog[0] = (f32x4){0.f, 0.f, 0.f, 0.f};
    plog[1] = (f32x4){0.f, 0.f, 0.f, 0.f};

    #pragma unroll
    for (int ch = 0; ch < 2; ++ch) {
        if ((wave & 1) == ch) {
            #pragma unroll
            for (int fm = 0; fm < 4; ++fm)
                #pragma unroll
                for (int r = 0; r < 4; ++r) {
                    int row = wm + fm * 16 + l4 * 4 + r;
                    int rx = (row & 7) << 4;
                    #pragma unroll
                    for (int fn = 0; fn < 4; ++fn) {
                        float hv = fmaxf(acc[fm][fn][r] + bcol[fn], 0.f);
                        unsigned short hh = f2bf(hv);
                        unsigned short hl = f2bf(hv - bf2f(hh));
                        int byteoff = row * 128 + ((((fn * 16 + l15) * 2)) ^ rx);
                        *reinterpret_cast<unsigned short*>(smem + byteoff) = hh;
                        *reinterpret_cast<unsigned short*>(smem + 16384 + byteoff) = hl;
                    }
                }
        }
        __syncthreads();

        #pragma unroll
        for (int fmm = 0; fmm < 2; ++fmm) {
            int rowb = wave * 32 + fmm * 16 + l15;
            int rx = (rowb & 7) << 4;
            int rowbase = rowb * 128;
            #pragma unroll
            for (int kc = 0; kc < 2; ++kc) {
                int co = kc * 64 + l4 * 16;
                s16x8 ahi = *reinterpret_cast<const s16x8*>(smem + rowbase + (co ^ rx));
                s16x8 alo = *reinterpret_cast<const s16x8*>(smem + 16384 + rowbase + (co ^ rx));
                int wb = W2T_OFS + ch * 128 + kc * 64 + l4 * 16;
                s16x8 whi = *reinterpret_cast<const s16x8*>(smem + wb + l15 * W2T_PITCH);
                s16x8 wlo = *reinterpret_cast<const s16x8*>(smem + wb + (l15 + 8) * W2T_PITCH);
                plog[fmm] = MFMA_B16(ahi, whi, plog[fmm], 0, 0, 0);
                plog[fmm] = MFMA_B16(ahi, wlo, plog[fmm], 0, 0, 0);
                plog[fmm] = MFMA_B16(alo, whi, plog[fmm], 0, 0, 0);
            }
        }
        __syncthreads();
    }

    // store partials: P rows = rb*128 + wave*32 + fmm*16 + l4*4 + r, expert = l15
    if (l15 < 8) {
        #pragma unroll
        for (int fmm = 0; fmm < 2; ++fmm) {
            int rowg = rb * 128 + wave * 32 + fmm * 16 + l4 * 4;
            #pragma unroll
            for (int r = 0; r < 4; ++r)
                Plog[((size_t)cb * 8192 + rowg + r) * E_NUM + l15] = plog[fmm][r];
        }
    }

    // ---- tail combine: 8th-arriving block per rb combines its 128 tokens ----
    __threadfence();                       // release partial stores (device scope)
    if (tid == 0) {
        int old = atomicAdd(&Cnt[rb], 1);
        *reinterpret_cast<int*>(smem + FLAG_OFS) = (old == 7) ? 1 : 0;
    }
    __syncthreads();
    if (*reinterpret_cast<const int*>(smem + FLAG_OFS)) {
        __threadfence();                   // acquire: other blocks' partials visible
        const int e = lane & 7;
        const float b2e = b2[e];
        for (int ti = wave; ti < 128; ti += 4) {
            const int t = rb * 128 + ti;
            // lane = cbi*8 + e reads partial [cbi][t][e]; xor-reduce over cbi
            float v = Plog[((size_t)(lane >> 3) * 8192 + t) * E_NUM + e];
            v += __shfl_xor(v, 8, 64);
            v += __shfl_xor(v, 16, 64);
            v += __shfl_xor(v, 32, 64);
            float logit = v + b2e;         // every lane: total logit for its e
            float lg[8];
            #pragma unroll
            for (int q = 0; q < 8; ++q) lg[q] = __shfl(logit, q, 64);
            float mx = lg[0];
            #pragma unroll
            for (int q = 1; q < 8; ++q) mx = fmaxf(mx, lg[q]);
            float p[8], ssum = 0.f;
            #pragma unroll
            for (int q = 0; q < 8; ++q) { p[q] = expf(lg[q] - mx); ssum += p[q]; }
            float inv = 1.f / ssum;
            #pragma unroll
            for (int q = 0; q < 8; ++q) p[q] *= inv;
            int e0 = 0;
            #pragma unroll
            for (int q = 1; q < 8; ++q) if (p[q] > p[e0]) e0 = q;
            int e1 = (e0 == 0) ? 1 : 0;
            #pragma unroll
            for (int q = 0; q < 8; ++q)
                if (q != e0 && q != e1 && p[q] > p[e1]) e1 = q;
            const float g0 = p[e0], g1 = p[e1];
            const float* x0 = EO + ((size_t)e0 * 8192 + t) * H_DIM;
            const float* x1 = EO + ((size_t)e1 * 8192 + t) * H_DIM;
            float* orow = Out + (size_t)t * H_DIM;
            #pragma unroll
            for (int it4 = 0; it4 < 4; ++it4) {
                int d = (it4 * 64 + lane) * 4;
                float4 a = *reinterpret_cast<const float4*>(x0 + d);
                float4 b = *reinterpret_cast<const float4*>(x1 + d);
                float4 o;
                o.x = g0 * a.x + g1 * b.x;
                o.y = g0 * a.y + g1 * b.y;
                o.z = g0 * a.z + g1 * b.z;
                o.w = g0 * a.w + g1 * b.w;
                *reinterpret_cast<float4*>(orow + d) = o;
            }
        }
    }
}

// ---------------- R1 fallback fp32 SGEMM + old combine (verified) ----------------
#define BM 128
#define BN 128
#define BK 16
#define PAD_LD 132

__global__ __launch_bounds__(256) void gemm1_relu_kernel(
    const float* __restrict__ A, const float* __restrict__ W,
    const float* __restrict__ bias, float* __restrict__ Hout,
    int M, int N, int K)
{
    __shared__ float As[BK][PAD_LD];
    __shared__ float Bs[BK][PAD_LD];
    const int tid = threadIdx.x;
    const int tx = tid & 15;
    const int ty = tid >> 4;
    const int row0 = blockIdx.y * BM;
    const int col0 = blockIdx.x * BN;
    float acc[8][8];
    #pragma unroll
    for (int i = 0; i < 8; ++i)
        #pragma unroll
        for (int j = 0; j < 8; ++j) acc[i][j] = 0.f;
    const int a_row = tid >> 2;
    const int a_k4  = (tid & 3) * 4;
    const int b_col4 = (tid & 31) * 4;
    const int b_kk   = tid >> 5;
    for (int k0 = 0; k0 < K; k0 += BK) {
        #pragma unroll
        for (int half = 0; half < 2; ++half) {
            int r = a_row + half * 64;
            float4 av = *reinterpret_cast<const float4*>(&A[(size_t)(row0 + r) * K + k0 + a_k4]);
            As[a_k4 + 0][r] = av.x; As[a_k4 + 1][r] = av.y;
            As[a_k4 + 2][r] = av.z; As[a_k4 + 3][r] = av.w;
        }
        #pragma unroll
        for (int half = 0; half < 2; ++half) {
            int kk = b_kk + half * 8;
            float4 bv = *reinterpret_cast<const float4*>(&W[(size_t)(k0 + kk) * N + col0 + b_col4]);
            *reinterpret_cast<float4*>(&Bs[kk][b_col4]) = bv;
        }
        __syncthreads();
        #pragma unroll
        for (int k = 0; k < BK; ++k) {
            float4 a0 = *reinterpret_cast<const float4*>(&As[k][ty * 8]);
            float4 a1 = *reinterpret_cast<const float4*>(&As[k][ty * 8 + 4]);
            float4 b0 = *reinterpret_cast<const float4*>(&Bs[k][tx * 8]);
            float4 b1 = *reinterpret_cast<const float4*>(&Bs[k][tx * 8 + 4]);
            float a[8] = {a0.x, a0.y, a0.z, a0.w, a1.x, a1.y, a1.z, a1.w};
            float b[8] = {b0.x, b0.y, b0.z, b0.w, b1.x, b1.y, b1.z, b1.w};
            #pragma unroll
            for (int i = 0; i < 8; ++i)
                #pragma unroll
                for (int j = 0; j < 8; ++j)
                    acc[i][j] = fmaf(a[i], b[j], acc[i][j]);
        }
        __syncthreads();
    }
    #pragma unroll
    for (int i = 0; i < 8; ++i) {
        int row = row0 + ty * 8 + i;
        #pragma unroll
        for (int j4 = 0; j4 < 2; ++j4) {
            int col = col0 + tx * 8 + j4 * 4;
            float4 v;
            v.x = fmaxf(acc[i][j4 * 4 + 0] + bias[col + 0], 0.f);
            v.y = fmaxf(acc[i][j4 * 4 + 1] + bias[col + 1], 0.f);
            v.z = fmaxf(acc[i][j4 * 4 + 2] + bias[col + 2], 0.f);
            v.w = fmaxf(acc[i][j4 * 4 + 3] + bias[col + 3], 0.f);
            *reinterpret_cast<float4*>(&Hout[(size_t)row * N + col]) = v;
        }
    }
}

__global__ __launch_bounds__(256) void route_combine_kernel(
    const float* __restrict__ Hbuf, const float* __restrict__ W2,
    const float* __restrict__ b2, const float* __restrict__ EO,
    float* __restrict__ Out, int M)
{
    const int t = blockIdx.x;
    const int tid = threadIdx.x;
    const int lane = tid & 63;
    const int wave = tid >> 6;
    const float* hrow = Hbuf + (size_t)t * H_DIM;

    float part[E_NUM];
    #pragma unroll
    for (int e = 0; e < E_NUM; ++e) part[e] = 0.f;
    #pragma unroll
    for (int it = 0; it < H_DIM / 256; ++it) {
        int j = tid + it * 256;
        float hv = hrow[j];
        const float* w = W2 + (size_t)j * E_NUM;
        #pragma unroll
        for (int e = 0; e < E_NUM; ++e) part[e] = fmaf(hv, w[e], part[e]);
    }
    #pragma unroll
    for (int off = 32; off > 0; off >>= 1)
        #pragma unroll
        for (int e = 0; e < E_NUM; ++e)
            part[e] += __shfl_down(part[e], off, 64);

    __shared__ float sred[4][E_NUM];
    __shared__ float s_g[2];
    __shared__ int   s_e[2];
    if (lane == 0)
        #pragma unroll
        for (int e = 0; e < E_NUM; ++e) sred[wave][e] = part[e];
    __syncthreads();

    if (tid == 0) {
        float logits[E_NUM];
        #pragma unroll
        for (int e = 0; e < E_NUM; ++e)
            logits[e] = sred[0][e] + sred[1][e] + sred[2][e] + sred[3][e] + b2[e];
        float m = logits[0];
        #pragma unroll
        for (int e = 1; e < E_NUM; ++e) m = fmaxf(m, logits[e]);
        float p[E_NUM], ssum = 0.f;
        #pragma unroll
        for (int e = 0; e < E_NUM; ++e) { p[e] = expf(logits[e] - m); ssum += p[e]; }
        float inv = 1.f / ssum;
        #pragma unroll
        for (int e = 0; e < E_NUM; ++e) p[e] *= inv;
        int e0 = 0;
        #pragma unroll
        for (int e = 1; e < E_NUM; ++e) if (p[e] > p[e0]) e0 = e;
        int e1 = (e0 == 0) ? 1 : 0;
        #pragma unroll
        for (int e = 0; e < E_NUM; ++e)
            if (e != e0 && e != e1 && p[e] > p[e1]) e1 = e;
        s_g[0] = p[e0]; s_g[1] = p[e1];
        s_e[0] = e0;    s_e[1] = e1;
    }
    __syncthreads();

    const float g0 = s_g[0], g1 = s_g[1];
    const size_t base0 = ((size_t)s_e[0] * M + t) * H_DIM;
    const size_t base1 = ((size_t)s_e[1] * M + t) * H_DIM;
    const int d = tid * 4;
    float4 x0 = *reinterpret_cast<const float4*>(&EO[base0 + d]);
    float4 x1 = *reinterpret_cast<const float4*>(&EO[base1 + d]);
    float4 o;
    o.x = g0 * x0.x + g1 * x1.x;
    o.y = g0 * x0.y + g1 * x1.y;
    o.z = g0 * x0.z + g1 * x1.z;
    o.w = g0 * x0.w + g1 * x1.w;
    *reinterpret_cast<float4*>(&Out[(size_t)t * H_DIM + d]) = o;
}

extern "C" void kernel_launch(void* const* d_in, const int* in_sizes, int n_in,
                              void* d_out, int out_size, void* d_ws, size_t ws_size,
                              hipStream_t stream)
{
    const float* hs = (const float*)d_in[0];
    const float* EO = (const float*)d_in[1];
    const float* W1 = (const float*)d_in[2];
    const float* b1 = (const float*)d_in[3];
    const float* W2 = (const float*)d_in[4];
    const float* b2 = (const float*)d_in[5];

    const int M = in_sizes[0] / H_DIM;   // 8192
    float* out = (float*)d_out;

    const size_t A_IMG = (size_t)64 * 32 * 16384;       // 33,554,432
    const size_t B_IMG = (size_t)8 * 32 * 16384;        //  4,194,304
    const size_t PART  = (size_t)8 * 8192 * 8 * 4;      //  2,097,152
    const size_t CNT   = 64 * sizeof(int);
    if (M == 8192 && ws_size >= A_IMG + B_IMG + PART + CNT) {
        char*  Aimg = (char*)d_ws;
        char*  Bimg = (char*)d_ws + A_IMG;
        float* Plog = (float*)((char*)d_ws + A_IMG + B_IMG);
        int*   Cnt  = (int*)((char*)d_ws + A_IMG + B_IMG + PART);
        hipMemsetAsync(Cnt, 0, CNT, stream);
        prep_fused_kernel<<<4096 + 512, 256, 0, stream>>>(hs, W1, Aimg, Bimg);
        gemm1_logits_kernel<<<512, 256, 0, stream>>>(Aimg, Bimg, b1, W2, Plog,
                                                     b2, EO, out, Cnt);
    } else {
        dim3 grid1(H_DIM / BN, M / BM);
        gemm1_relu_kernel<<<grid1, 256, 0, stream>>>(hs, W1, b1, out, M, H_DIM, H_DIM);
        route_combine_kernel<<<M, 256, 0, stream>>>(out, W2, b2, EO, out, M);
    }
}

// Round 8
// 88.655 us; speedup vs baseline: 2.0434x; 2.0434x over previous
//
#include <hip/hip_runtime.h>
#include <math.h>

// ExpertGating: h=relu(hs@W1+b1); logits=h@W2+b2; softmax; top-2; combine.
// R8: R6 structure (logits fused in GEMM epilogue, separate 8192-block combine
// -- R7's 64-block tail combine regressed 2.2x, reverted). Single change:
// main-loop MFMA 16x16x32 -> 32x32x16 (+15% pipe rate, half the instructions).
// C/D map 32x32: col=lane&31, row=(reg&3)+8*(reg>>2)+4*(lane>>5)  [m74/m101].
// A/B operand: row(col)=lane&31, k-octet=lane>>5. Logits epilogue stays 16x16.

#define H_DIM 1024
#define E_NUM 8

typedef __attribute__((ext_vector_type(8))) short s16x8;
typedef __attribute__((ext_vector_type(8))) unsigned short u16x8;
typedef __attribute__((ext_vector_type(4))) float f32x4;
typedef __attribute__((ext_vector_type(16))) float f32x16;

__device__ __forceinline__ unsigned short f2bf(float x) {
    unsigned int u = __float_as_uint(x);
    unsigned int r = (u + 0x7FFFu + ((u >> 16) & 1u)) >> 16;
    return (unsigned short)r;
}
__device__ __forceinline__ float bf2f(unsigned short b) {
    return __uint_as_float(((unsigned int)b) << 16);
}
__device__ __forceinline__ void gload_lds16(const void* g, void* lds) {
    __builtin_amdgcn_global_load_lds(
        (const __attribute__((address_space(1))) void*)g,
        (__attribute__((address_space(3))) void*)lds, 16, 0, 0);
}

// ---------------- fused prep: hs and W1 -> swizzled hi/lo bf16 images --------
// Image tile = 128 rows x 128 B (8 slots of 16B: slots 0-3 hi k-octets, 4-7 lo),
// logical slot s stored at physical slot s ^ (row&7).
__global__ __launch_bounds__(256) void prep_fused_kernel(
    const float* __restrict__ A, const float* __restrict__ W,
    char* __restrict__ Aimg, char* __restrict__ Bimg)
{
    if (blockIdx.x < 4096) {
        int t = blockIdx.x * 256 + threadIdx.x;   // 8192 rows x 128 octets
        int m = t >> 7;
        int k = (t & 127) << 3;
        const float* src = A + ((size_t)m << 10) + k;
        float4 v0 = *reinterpret_cast<const float4*>(src);
        float4 v1 = *reinterpret_cast<const float4*>(src + 4);
        float xs[8] = {v0.x, v0.y, v0.z, v0.w, v1.x, v1.y, v1.z, v1.w};
        u16x8 hv, lv;
        #pragma unroll
        for (int j = 0; j < 8; ++j) {
            unsigned short h = f2bf(xs[j]);
            hv[j] = h;
            lv[j] = f2bf(xs[j] - bf2f(h));
        }
        int rb = m >> 7, mr = m & 127, kt = k >> 5, s = (k >> 3) & 3;
        char* base = Aimg + (((size_t)(rb * 32 + kt)) << 14) + mr * 128;
        *reinterpret_cast<u16x8*>(base + ((s ^ (mr & 7)) << 4)) = hv;
        *reinterpret_cast<u16x8*>(base + (((s + 4) ^ (mr & 7)) << 4)) = lv;
    } else {
        int t = (blockIdx.x - 4096) * 256 + threadIdx.x;  // 1024 cols x 128 octets
        int n = t & 1023;
        int k = (t >> 10) << 3;
        u16x8 hv, lv;
        #pragma unroll
        for (int j = 0; j < 8; ++j) {
            float x = W[((size_t)(k + j) << 10) + n];
            unsigned short h = f2bf(x);
            hv[j] = h;
            lv[j] = f2bf(x - bf2f(h));
        }
        int cb = n >> 7, nr = n & 127, kt = k >> 5, s = (k >> 3) & 3;
        char* base = Bimg + (((size_t)(cb * 32 + kt)) << 14) + nr * 128;
        *reinterpret_cast<u16x8*>(base + ((s ^ (nr & 7)) << 4)) = hv;
        *reinterpret_cast<u16x8*>(base + (((s + 4) ^ (nr & 7)) << 4)) = lv;
    }
}

// ---------------- GEMM1 (32x32x16) + fused router logits (16x16x32) ----------
// LDS map: [0,16384)=As / h_hi[128][64]; [16384,32768)=Bs / h_lo[128][64];
//          [32768,39296)=w2t 24 rows x 272B (rows 0-7 hi, 8-15 lo, 16-23 zero)
#define MFMA_B16 __builtin_amdgcn_mfma_f32_16x16x32_bf16
#define MFMA32   __builtin_amdgcn_mfma_f32_32x32x16_bf16
#define W2T_OFS 32768
#define W2T_PITCH 272

__global__ __launch_bounds__(256, 3) void gemm1_logits_kernel(
    const char* __restrict__ Aimg, const char* __restrict__ Bimg,
    const float* __restrict__ bias, const float* __restrict__ W2,
    float* __restrict__ Plog)
{
    __shared__ char smem[39296];

    int bid = blockIdx.x;
    int swz = (bid & 7) * 64 + (bid >> 3);   // bijective, 512 % 8 == 0
    int rb = swz >> 3;          // 0..63
    int cb = swz & 7;           // 0..7

    int tid = threadIdx.x;
    int lane = tid & 63;
    int wave = tid >> 6;
    int wm = (wave >> 1) * 64;
    int wn = (wave & 1) * 64;
    int l31 = lane & 31, l1 = lane >> 5;     // 32x32 fragment coords
    int l15 = lane & 15, l4 = lane >> 4;     // 16x16 (logits) coords

    // ---- w2t: zero, then fill hi/lo bf16 of W2 slice (transposed) ----
    const int col0g = cb * 128;
    for (int i = tid; i < 1632; i += 256)
        *reinterpret_cast<float*>(smem + W2T_OFS + i * 4) = 0.f;
    __syncthreads();
    {
        int e = tid & 7, c4 = tid >> 3;   // c4: 0..31
        #pragma unroll
        for (int j = 0; j < 4; ++j) {
            int col = c4 * 4 + j;
            float w = W2[(size_t)(col0g + col) * E_NUM + e];
            unsigned short wh = f2bf(w);
            unsigned short wl = f2bf(w - bf2f(wh));
            *reinterpret_cast<unsigned short*>(smem + W2T_OFS + e * W2T_PITCH + col * 2) = wh;
            *reinterpret_cast<unsigned short*>(smem + W2T_OFS + (e + 8) * W2T_PITCH + col * 2) = wl;
        }
    }
    __syncthreads();

    // fragment LDS offsets for 32x32x16 (swizzle baked in)
    // A frag (m, ks): row = wm + m*32 + l31, k-octet = ks*2 + l1 (hi), +4 (lo)
    int aoff_h[2][2], aoff_l[2][2], boff_h[2][2], boff_l[2][2];
    #pragma unroll
    for (int m = 0; m < 2; ++m) {
        int ar = wm + m * 32 + l31;
        int arx = ar & 7;
        #pragma unroll
        for (int ks = 0; ks < 2; ++ks) {
            int s = ks * 2 + l1;
            aoff_h[m][ks] = ar * 128 + ((s ^ arx) << 4);
            aoff_l[m][ks] = ar * 128 + (((s + 4) ^ arx) << 4);
        }
    }
    #pragma unroll
    for (int n = 0; n < 2; ++n) {
        int br = wn + n * 32 + l31;
        int brx = br & 7;
        #pragma unroll
        for (int ks = 0; ks < 2; ++ks) {
            int s = ks * 2 + l1;
            boff_h[n][ks] = 16384 + br * 128 + ((s ^ brx) << 4);
            boff_l[n][ks] = 16384 + br * 128 + (((s + 4) ^ brx) << 4);
        }
    }

    const char* abase = Aimg + (size_t)rb * (32 * 16384);
    const char* bbase = Bimg + (size_t)cb * (32 * 16384);

    f32x16 acc[2][2];
    #pragma unroll
    for (int m = 0; m < 2; ++m)
        #pragma unroll
        for (int n = 0; n < 2; ++n)
            #pragma unroll
            for (int i = 0; i < 16; ++i)
                acc[m][n][i] = 0.f;

    for (int kt = 0; kt < 32; ++kt) {
        const char* ga = abase + (kt << 14);
        const char* gb = bbase + (kt << 14);
        int toff = tid << 4;
        #pragma unroll
        for (int r = 0; r < 4; ++r) {
            gload_lds16(ga + (r << 12) + toff, smem + (r << 12) + toff);
            gload_lds16(gb + (r << 12) + toff, smem + 16384 + (r << 12) + toff);
        }
        __syncthreads();

        s16x8 ah[2][2], al[2][2], bh[2][2], bl[2][2];
        #pragma unroll
        for (int m = 0; m < 2; ++m)
            #pragma unroll
            for (int ks = 0; ks < 2; ++ks) {
                ah[m][ks] = *reinterpret_cast<const s16x8*>(smem + aoff_h[m][ks]);
                al[m][ks] = *reinterpret_cast<const s16x8*>(smem + aoff_l[m][ks]);
            }
        #pragma unroll
        for (int n = 0; n < 2; ++n)
            #pragma unroll
            for (int ks = 0; ks < 2; ++ks) {
                bh[n][ks] = *reinterpret_cast<const s16x8*>(smem + boff_h[n][ks]);
                bl[n][ks] = *reinterpret_cast<const s16x8*>(smem + boff_l[n][ks]);
            }
        // 3-pass split: hh, hl, lh; ks inner-most grouping keeps acc reuse dist 4
        #pragma unroll
        for (int ks = 0; ks < 2; ++ks)
            #pragma unroll
            for (int m = 0; m < 2; ++m)
                #pragma unroll
                for (int n = 0; n < 2; ++n)
                    acc[m][n] = MFMA32(ah[m][ks], bh[n][ks], acc[m][n], 0, 0, 0);
        #pragma unroll
        for (int ks = 0; ks < 2; ++ks)
            #pragma unroll
            for (int m = 0; m < 2; ++m)
                #pragma unroll
                for (int n = 0; n < 2; ++n)
                    acc[m][n] = MFMA32(ah[m][ks], bl[n][ks], acc[m][n], 0, 0, 0);
        #pragma unroll
        for (int ks = 0; ks < 2; ++ks)
            #pragma unroll
            for (int m = 0; m < 2; ++m)
                #pragma unroll
                for (int n = 0; n < 2; ++n)
                    acc[m][n] = MFMA32(al[m][ks], bh[n][ks], acc[m][n], 0, 0, 0);
        __syncthreads();
    }

    // ---- fused epilogue: P[row][e] = relu(acc + b1) @ W2slice, 3-pass split ----
    float bcol[2];
    #pragma unroll
    for (int n = 0; n < 2; ++n) bcol[n] = bias[col0g + wn + n * 32 + l31];

    f32x4 plog[2];
    plog[0] = (f32x4){0.f, 0.f, 0.f, 0.f};
    plog[1] = (f32x4){0.f, 0.f, 0.f, 0.f};

    #pragma unroll
    for (int ch = 0; ch < 2; ++ch) {
        // waves owning col-half ch write h hi/lo (swizzled) into As/Bs region.
        // 32x32 C/D map: row = wm + m*32 + (reg&3) + 8*(reg>>2) + 4*(lane>>5),
        //                col (within half) = n*32 + l31.
        if ((wave & 1) == ch) {
            #pragma unroll
            for (int m = 0; m < 2; ++m)
                #pragma unroll
                for (int reg = 0; reg < 16; ++reg) {
                    int row = wm + m * 32 + (reg & 3) + 8 * (reg >> 2) + 4 * l1;
                    int rx = (row & 7) << 4;
                    #pragma unroll
                    for (int n = 0; n < 2; ++n) {
                        float hv = fmaxf(acc[m][n][reg] + bcol[n], 0.f);
                        unsigned short hh = f2bf(hv);
                        unsigned short hl = f2bf(hv - bf2f(hh));
                        int byteoff = row * 128 + ((((n * 32 + l31) * 2)) ^ rx);
                        *reinterpret_cast<unsigned short*>(smem + byteoff) = hh;
                        *reinterpret_cast<unsigned short*>(smem + 16384 + byteoff) = hl;
                    }
                }
        }
        __syncthreads();

        // all waves: logits MFMA over this 64-col half (16x16x32, verified R6)
        #pragma unroll
        for (int fmm = 0; fmm < 2; ++fmm) {
            int rowb = wave * 32 + fmm * 16 + l15;
            int rx = (rowb & 7) << 4;
            int rowbase = rowb * 128;
            #pragma unroll
            for (int kc = 0; kc < 2; ++kc) {
                int co = kc * 64 + l4 * 16;
                s16x8 ahi = *reinterpret_cast<const s16x8*>(smem + rowbase + (co ^ rx));
                s16x8 alo = *reinterpret_cast<const s16x8*>(smem + 16384 + rowbase + (co ^ rx));
                int wb = W2T_OFS + ch * 128 + kc * 64 + l4 * 16;
                s16x8 whi = *reinterpret_cast<const s16x8*>(smem + wb + l15 * W2T_PITCH);
                s16x8 wlo = *reinterpret_cast<const s16x8*>(smem + wb + (l15 + 8) * W2T_PITCH);
                plog[fmm] = MFMA_B16(ahi, whi, plog[fmm], 0, 0, 0);
                plog[fmm] = MFMA_B16(ahi, wlo, plog[fmm], 0, 0, 0);
                plog[fmm] = MFMA_B16(alo, whi, plog[fmm], 0, 0, 0);
            }
        }
        __syncthreads();
    }

    // store partials: P rows = rb*128 + wave*32 + fmm*16 + l4*4 + r, expert = l15
    if (l15 < 8) {
        #pragma unroll
        for (int fmm = 0; fmm < 2; ++fmm) {
            int rowg = rb * 128 + wave * 32 + fmm * 16 + l4 * 4;
            #pragma unroll
            for (int r = 0; r < 4; ++r)
                Plog[((size_t)cb * 8192 + rowg + r) * E_NUM + l15] = plog[fmm][r];
        }
    }
}

// ---------------- combine: reduce partials -> softmax -> top2 -> gather ------
__global__ __launch_bounds__(256) void route_combine2_kernel(
    const float* __restrict__ Plog, const float* __restrict__ b2,
    const float* __restrict__ EO, float* __restrict__ Out, int M)
{
    const int t = blockIdx.x;
    const int tid = threadIdx.x;

    __shared__ float s_logit[E_NUM];
    __shared__ float s_g[2];
    __shared__ int   s_e[2];

    if (tid < 64) {
        int cbi = tid >> 3, e = tid & 7;
        float v = Plog[((size_t)cbi * M + t) * E_NUM + e];
        v += __shfl_xor(v, 8, 64);
        v += __shfl_xor(v, 16, 64);
        v += __shfl_xor(v, 32, 64);
        if (tid < 8) s_logit[tid] = v + b2[tid];
    }
    __syncthreads();

    if (tid == 0) {
        float logits[E_NUM];
        #pragma unroll
        for (int e = 0; e < E_NUM; ++e) logits[e] = s_logit[e];
        float m = logits[0];
        #pragma unroll
        for (int e = 1; e < E_NUM; ++e) m = fmaxf(m, logits[e]);
        float p[E_NUM], ssum = 0.f;
        #pragma unroll
        for (int e = 0; e < E_NUM; ++e) { p[e] = expf(logits[e] - m); ssum += p[e]; }
        float inv = 1.f / ssum;
        #pragma unroll
        for (int e = 0; e < E_NUM; ++e) p[e] *= inv;
        int e0 = 0;
        #pragma unroll
        for (int e = 1; e < E_NUM; ++e) if (p[e] > p[e0]) e0 = e;
        int e1 = (e0 == 0) ? 1 : 0;
        #pragma unroll
        for (int e = 0; e < E_NUM; ++e)
            if (e != e0 && e != e1 && p[e] > p[e1]) e1 = e;
        s_g[0] = p[e0]; s_g[1] = p[e1];
        s_e[0] = e0;    s_e[1] = e1;
    }
    __syncthreads();

    const float g0 = s_g[0], g1 = s_g[1];
    const size_t base0 = ((size_t)s_e[0] * M + t) * H_DIM;
    const size_t base1 = ((size_t)s_e[1] * M + t) * H_DIM;
    const int d = tid * 4;
    float4 x0 = *reinterpret_cast<const float4*>(&EO[base0 + d]);
    float4 x1 = *reinterpret_cast<const float4*>(&EO[base1 + d]);
    float4 o;
    o.x = g0 * x0.x + g1 * x1.x;
    o.y = g0 * x0.y + g1 * x1.y;
    o.z = g0 * x0.z + g1 * x1.z;
    o.w = g0 * x0.w + g1 * x1.w;
    *reinterpret_cast<float4*>(&Out[(size_t)t * H_DIM + d]) = o;
}

// ---------------- R1 fallback fp32 SGEMM + old combine (verified) ----------------
#define BM 128
#define BN 128
#define BK 16
#define PAD_LD 132

__global__ __launch_bounds__(256) void gemm1_relu_kernel(
    const float* __restrict__ A, const float* __restrict__ W,
    const float* __restrict__ bias, float* __restrict__ Hout,
    int M, int N, int K)
{
    __shared__ float As[BK][PAD_LD];
    __shared__ float Bs[BK][PAD_LD];
    const int tid = threadIdx.x;
    const int tx = tid & 15;
    const int ty = tid >> 4;
    const int row0 = blockIdx.y * BM;
    const int col0 = blockIdx.x * BN;
    float acc[8][8];
    #pragma unroll
    for (int i = 0; i < 8; ++i)
        #pragma unroll
        for (int j = 0; j < 8; ++j) acc[i][j] = 0.f;
    const int a_row = tid >> 2;
    const int a_k4  = (tid & 3) * 4;
    const int b_col4 = (tid & 31) * 4;
    const int b_kk   = tid >> 5;
    for (int k0 = 0; k0 < K; k0 += BK) {
        #pragma unroll
        for (int half = 0; half < 2; ++half) {
            int r = a_row + half * 64;
            float4 av = *reinterpret_cast<const float4*>(&A[(size_t)(row0 + r) * K + k0 + a_k4]);
            As[a_k4 + 0][r] = av.x; As[a_k4 + 1][r] = av.y;
            As[a_k4 + 2][r] = av.z; As[a_k4 + 3][r] = av.w;
        }
        #pragma unroll
        for (int half = 0; half < 2; ++half) {
            int kk = b_kk + half * 8;
            float4 bv = *reinterpret_cast<const float4*>(&W[(size_t)(k0 + kk) * N + col0 + b_col4]);
            *reinterpret_cast<float4*>(&Bs[kk][b_col4]) = bv;
        }
        __syncthreads();
        #pragma unroll
        for (int k = 0; k < BK; ++k) {
            float4 a0 = *reinterpret_cast<const float4*>(&As[k][ty * 8]);
            float4 a1 = *reinterpret_cast<const float4*>(&As[k][ty * 8 + 4]);
            float4 b0 = *reinterpret_cast<const float4*>(&Bs[k][tx * 8]);
            float4 b1 = *reinterpret_cast<const float4*>(&Bs[k][tx * 8 + 4]);
            float a[8] = {a0.x, a0.y, a0.z, a0.w, a1.x, a1.y, a1.z, a1.w};
            float b[8] = {b0.x, b0.y, b0.z, b0.w, b1.x, b1.y, b1.z, b1.w};
            #pragma unroll
            for (int i = 0; i < 8; ++i)
                #pragma unroll
                for (int j = 0; j < 8; ++j)
                    acc[i][j] = fmaf(a[i], b[j], acc[i][j]);
        }
        __syncthreads();
    }
    #pragma unroll
    for (int i = 0; i < 8; ++i) {
        int row = row0 + ty * 8 + i;
        #pragma unroll
        for (int j4 = 0; j4 < 2; ++j4) {
            int col = col0 + tx * 8 + j4 * 4;
            float4 v;
            v.x = fmaxf(acc[i][j4 * 4 + 0] + bias[col + 0], 0.f);
            v.y = fmaxf(acc[i][j4 * 4 + 1] + bias[col + 1], 0.f);
            v.z = fmaxf(acc[i][j4 * 4 + 2] + bias[col + 2], 0.f);
            v.w = fmaxf(acc[i][j4 * 4 + 3] + bias[col + 3], 0.f);
            *reinterpret_cast<float4*>(&Hout[(size_t)row * N + col]) = v;
        }
    }
}

__global__ __launch_bounds__(256) void route_combine_kernel(
    const float* __restrict__ Hbuf, const float* __restrict__ W2,
    const float* __restrict__ b2, const float* __restrict__ EO,
    float* __restrict__ Out, int M)
{
    const int t = blockIdx.x;
    const int tid = threadIdx.x;
    const int lane = tid & 63;
    const int wave = tid >> 6;
    const float* hrow = Hbuf + (size_t)t * H_DIM;

    float part[E_NUM];
    #pragma unroll
    for (int e = 0; e < E_NUM; ++e) part[e] = 0.f;
    #pragma unroll
    for (int it = 0; it < H_DIM / 256; ++it) {
        int j = tid + it * 256;
        float hv = hrow[j];
        const float* w = W2 + (size_t)j * E_NUM;
        #pragma unroll
        for (int e = 0; e < E_NUM; ++e) part[e] = fmaf(hv, w[e], part[e]);
    }
    #pragma unroll
    for (int off = 32; off > 0; off >>= 1)
        #pragma unroll
        for (int e = 0; e < E_NUM; ++e)
            part[e] += __shfl_down(part[e], off, 64);

    __shared__ float sred[4][E_NUM];
    __shared__ float s_g[2];
    __shared__ int   s_e[2];
    if (lane == 0)
        #pragma unroll
        for (int e = 0; e < E_NUM; ++e) sred[wave][e] = part[e];
    __syncthreads();

    if (tid == 0) {
        float logits[E_NUM];
        #pragma unroll
        for (int e = 0; e < E_NUM; ++e)
            logits[e] = sred[0][e] + sred[1][e] + sred[2][e] + sred[3][e] + b2[e];
        float m = logits[0];
        #pragma unroll
        for (int e = 1; e < E_NUM; ++e) m = fmaxf(m, logits[e]);
        float p[E_NUM], ssum = 0.f;
        #pragma unroll
        for (int e = 0; e < E_NUM; ++e) { p[e] = expf(logits[e] - m); ssum += p[e]; }
        float inv = 1.f / ssum;
        #pragma unroll
        for (int e = 0; e < E_NUM; ++e) p[e] *= inv;
        int e0 = 0;
        #pragma unroll
        for (int e = 1; e < E_NUM; ++e) if (p[e] > p[e0]) e0 = e;
        int e1 = (e0 == 0) ? 1 : 0;
        #pragma unroll
        for (int e = 0; e < E_NUM; ++e)
            if (e != e0 && e != e1 && p[e] > p[e1]) e1 = e;
        s_g[0] = p[e0]; s_g[1] = p[e1];
        s_e[0] = e0;    s_e[1] = e1;
    }
    __syncthreads();

    const float g0 = s_g[0], g1 = s_g[1];
    const size_t base0 = ((size_t)s_e[0] * M + t) * H_DIM;
    const size_t base1 = ((size_t)s_e[1] * M + t) * H_DIM;
    const int d = tid * 4;
    float4 x0 = *reinterpret_cast<const float4*>(&EO[base0 + d]);
    float4 x1 = *reinterpret_cast<const float4*>(&EO[base1 + d]);
    float4 o;
    o.x = g0 * x0.x + g1 * x1.x;
    o.y = g0 * x0.y + g1 * x1.y;
    o.z = g0 * x0.z + g1 * x1.z;
    o.w = g0 * x0.w + g1 * x1.w;
    *reinterpret_cast<float4*>(&Out[(size_t)t * H_DIM + d]) = o;
}

extern "C" void kernel_launch(void* const* d_in, const int* in_sizes, int n_in,
                              void* d_out, int out_size, void* d_ws, size_t ws_size,
                              hipStream_t stream)
{
    const float* hs = (const float*)d_in[0];
    const float* EO = (const float*)d_in[1];
    const float* W1 = (const float*)d_in[2];
    const float* b1 = (const float*)d_in[3];
    const float* W2 = (const float*)d_in[4];
    const float* b2 = (const float*)d_in[5];

    const int M = in_sizes[0] / H_DIM;   // 8192
    float* out = (float*)d_out;

    const size_t A_IMG = (size_t)64 * 32 * 16384;       // 33,554,432
    const size_t B_IMG = (size_t)8 * 32 * 16384;        //  4,194,304
    const size_t PART  = (size_t)8 * 8192 * 8 * 4;      //  2,097,152
    if (M == 8192 && ws_size >= A_IMG + B_IMG + PART) {
        char*  Aimg = (char*)d_ws;
        char*  Bimg = (char*)d_ws + A_IMG;
        float* Plog = (float*)((char*)d_ws + A_IMG + B_IMG);
        prep_fused_kernel<<<4096 + 512, 256, 0, stream>>>(hs, W1, Aimg, Bimg);
        gemm1_logits_kernel<<<512, 256, 0, stream>>>(Aimg, Bimg, b1, W2, Plog);
        route_combine2_kernel<<<M, 256, 0, stream>>>(Plog, b2, EO, out, M);
    } else {
        dim3 grid1(H_DIM / BN, M / BM);
        gemm1_relu_kernel<<<grid1, 256, 0, stream>>>(hs, W1, b1, out, M, H_DIM, H_DIM);
        route_combine_kernel<<<M, 256, 0, stream>>>(out, W2, b2, EO, out, M);
    }
}

// Round 9
// 86.389 us; speedup vs baseline: 2.0970x; 1.0262x over previous
//
#include <hip/hip_runtime.h>
#include <math.h>

// ExpertGating: h=relu(hs@W1+b1); logits=h@W2+b2; softmax; top-2; combine.
// R9: R6 structure (16x16x32 3-pass split-bf16, fused logits epilogue, separate
// combine). Single change: T3-minimum one-tile-deep prefetch in the GEMM loop:
//   STAGE(next tile -> other LDS buffer) BEFORE ds_read+MFMA of current tile,
//   then ONE vmcnt(0) + s_barrier AFTER the MFMA cluster (drain hidden under
//   ~48 MFMAs instead of exposed). LDS: A dbuf 2x16K @0/16K, B dbuf @32K/48K,
//   w2t @64K (total 70.4KB -> 2 blocks/CU = what the 512-block grid gives).

#define H_DIM 1024
#define E_NUM 8

typedef __attribute__((ext_vector_type(8))) short s16x8;
typedef __attribute__((ext_vector_type(8))) unsigned short u16x8;
typedef __attribute__((ext_vector_type(4))) float f32x4;

__device__ __forceinline__ unsigned short f2bf(float x) {
    unsigned int u = __float_as_uint(x);
    unsigned int r = (u + 0x7FFFu + ((u >> 16) & 1u)) >> 16;
    return (unsigned short)r;
}
__device__ __forceinline__ float bf2f(unsigned short b) {
    return __uint_as_float(((unsigned int)b) << 16);
}
__device__ __forceinline__ void gload_lds16(const void* g, void* lds) {
    __builtin_amdgcn_global_load_lds(
        (const __attribute__((address_space(1))) void*)g,
        (__attribute__((address_space(3))) void*)lds, 16, 0, 0);
}

// ---------------- fused prep: hs and W1 -> swizzled hi/lo bf16 images --------
// Image tile = 128 rows x 128 B (8 slots of 16B: slots 0-3 hi k-octets, 4-7 lo),
// logical slot s stored at physical slot s ^ (row&7).
__global__ __launch_bounds__(256) void prep_fused_kernel(
    const float* __restrict__ A, const float* __restrict__ W,
    char* __restrict__ Aimg, char* __restrict__ Bimg)
{
    if (blockIdx.x < 4096) {
        int t = blockIdx.x * 256 + threadIdx.x;   // 8192 rows x 128 octets
        int m = t >> 7;
        int k = (t & 127) << 3;
        const float* src = A + ((size_t)m << 10) + k;
        float4 v0 = *reinterpret_cast<const float4*>(src);
        float4 v1 = *reinterpret_cast<const float4*>(src + 4);
        float xs[8] = {v0.x, v0.y, v0.z, v0.w, v1.x, v1.y, v1.z, v1.w};
        u16x8 hv, lv;
        #pragma unroll
        for (int j = 0; j < 8; ++j) {
            unsigned short h = f2bf(xs[j]);
            hv[j] = h;
            lv[j] = f2bf(xs[j] - bf2f(h));
        }
        int rb = m >> 7, mr = m & 127, kt = k >> 5, s = (k >> 3) & 3;
        char* base = Aimg + (((size_t)(rb * 32 + kt)) << 14) + mr * 128;
        *reinterpret_cast<u16x8*>(base + ((s ^ (mr & 7)) << 4)) = hv;
        *reinterpret_cast<u16x8*>(base + (((s + 4) ^ (mr & 7)) << 4)) = lv;
    } else {
        int t = (blockIdx.x - 4096) * 256 + threadIdx.x;  // 1024 cols x 128 octets
        int n = t & 1023;
        int k = (t >> 10) << 3;
        u16x8 hv, lv;
        #pragma unroll
        for (int j = 0; j < 8; ++j) {
            float x = W[((size_t)(k + j) << 10) + n];
            unsigned short h = f2bf(x);
            hv[j] = h;
            lv[j] = f2bf(x - bf2f(h));
        }
        int cb = n >> 7, nr = n & 127, kt = k >> 5, s = (k >> 3) & 3;
        char* base = Bimg + (((size_t)(cb * 32 + kt)) << 14) + nr * 128;
        *reinterpret_cast<u16x8*>(base + ((s ^ (nr & 7)) << 4)) = hv;
        *reinterpret_cast<u16x8*>(base + (((s + 4) ^ (nr & 7)) << 4)) = lv;
    }
}

// ---------------- GEMM1 + fused router logits, prefetched staging ----------
// LDS: A0 [0,16K) A1 [16K,32K) B0 [32K,48K) B1 [48K,64K) w2t [64K,70.4K)
// Epilogue reuses A0 = h_hi[128][64], A1 = h_lo[128][64].
#define MFMA_B16 __builtin_amdgcn_mfma_f32_16x16x32_bf16
#define W2T_OFS 65536
#define W2T_PITCH 272

__global__ __launch_bounds__(256, 2) void gemm1_logits_kernel(
    const char* __restrict__ Aimg, const char* __restrict__ Bimg,
    const float* __restrict__ bias, const float* __restrict__ W2,
    float* __restrict__ Plog)
{
    __shared__ char smem[72064];

    int bid = blockIdx.x;
    int swz = (bid & 7) * 64 + (bid >> 3);   // bijective, 512 % 8 == 0
    int rb = swz >> 3;          // 0..63
    int cb = swz & 7;           // 0..7

    int tid = threadIdx.x;
    int lane = tid & 63;
    int wave = tid >> 6;
    int wm = (wave >> 1) * 64;
    int wn = (wave & 1) * 64;
    int l15 = lane & 15, l4 = lane >> 4;

    // ---- w2t: zero, then fill hi/lo bf16 of W2 slice (transposed) ----
    const int col0g = cb * 128;
    for (int i = tid; i < 1632; i += 256)
        *reinterpret_cast<float*>(smem + W2T_OFS + i * 4) = 0.f;
    __syncthreads();
    {
        int e = tid & 7, c4 = tid >> 3;   // c4: 0..31
        #pragma unroll
        for (int j = 0; j < 4; ++j) {
            int col = c4 * 4 + j;
            float w = W2[(size_t)(col0g + col) * E_NUM + e];
            unsigned short wh = f2bf(w);
            unsigned short wl = f2bf(w - bf2f(wh));
            *reinterpret_cast<unsigned short*>(smem + W2T_OFS + e * W2T_PITCH + col * 2) = wh;
            *reinterpret_cast<unsigned short*>(smem + W2T_OFS + (e + 8) * W2T_PITCH + col * 2) = wl;
        }
    }
    __syncthreads();

    // fragment LDS offsets (tile-relative, swizzle baked in)
    int aoff_h[4], aoff_l[4], boff_h[4], boff_l[4];
    #pragma unroll
    for (int f = 0; f < 4; ++f) {
        int ar = wm + f * 16 + l15;
        aoff_h[f] = ar * 128 + ((l4 ^ (ar & 7)) << 4);
        aoff_l[f] = ar * 128 + (((l4 + 4) ^ (ar & 7)) << 4);
        int br = wn + f * 16 + l15;
        boff_h[f] = br * 128 + ((l4 ^ (br & 7)) << 4);
        boff_l[f] = br * 128 + (((l4 + 4) ^ (br & 7)) << 4);
    }

    const char* abase = Aimg + (size_t)rb * (32 * 16384);
    const char* bbase = Bimg + (size_t)cb * (32 * 16384);
    const int toff = tid << 4;

#define STAGE(kt_, aO, bO) do {                                              \
    const char* ga_ = abase + (((size_t)(kt_)) << 14);                       \
    const char* gb_ = bbase + (((size_t)(kt_)) << 14);                       \
    gload_lds16(ga_ + toff,         smem + (aO) + toff);                     \
    gload_lds16(ga_ + 4096 + toff,  smem + (aO) + 4096 + toff);              \
    gload_lds16(ga_ + 8192 + toff,  smem + (aO) + 8192 + toff);              \
    gload_lds16(ga_ + 12288 + toff, smem + (aO) + 12288 + toff);             \
    gload_lds16(gb_ + toff,         smem + (bO) + toff);                     \
    gload_lds16(gb_ + 4096 + toff,  smem + (bO) + 4096 + toff);              \
    gload_lds16(gb_ + 8192 + toff,  smem + (bO) + 8192 + toff);              \
    gload_lds16(gb_ + 12288 + toff, smem + (bO) + 12288 + toff);             \
} while (0)

    f32x4 acc[4][4];
    #pragma unroll
    for (int i = 0; i < 4; ++i)
        #pragma unroll
        for (int j = 0; j < 4; ++j)
            acc[i][j] = (f32x4){0.f, 0.f, 0.f, 0.f};

    // prologue: tile 0 -> buffer 0
    STAGE(0, 0, 32768);
    asm volatile("s_waitcnt vmcnt(0)" ::: "memory");
    asm volatile("s_barrier" ::: "memory");

    for (int kt = 0; kt < 32; ++kt) {
        const int cur = kt & 1;
        const char* As = smem + cur * 16384;
        const char* Bs = smem + 32768 + cur * 16384;

        if (kt < 31)
            STAGE(kt + 1, (cur ^ 1) * 16384, 32768 + (cur ^ 1) * 16384);

        s16x8 ah[4], al[4], bh[4], bl[4];
        #pragma unroll
        for (int f = 0; f < 4; ++f) {
            ah[f] = *reinterpret_cast<const s16x8*>(As + aoff_h[f]);
            al[f] = *reinterpret_cast<const s16x8*>(As + aoff_l[f]);
            bh[f] = *reinterpret_cast<const s16x8*>(Bs + boff_h[f]);
            bl[f] = *reinterpret_cast<const s16x8*>(Bs + boff_l[f]);
        }
        #pragma unroll
        for (int m = 0; m < 4; ++m)
            #pragma unroll
            for (int n = 0; n < 4; ++n)
                acc[m][n] = MFMA_B16(ah[m], bh[n], acc[m][n], 0, 0, 0);
        #pragma unroll
        for (int m = 0; m < 4; ++m)
            #pragma unroll
            for (int n = 0; n < 4; ++n)
                acc[m][n] = MFMA_B16(ah[m], bl[n], acc[m][n], 0, 0, 0);
        #pragma unroll
        for (int m = 0; m < 4; ++m)
            #pragma unroll
            for (int n = 0; n < 4; ++n)
                acc[m][n] = MFMA_B16(al[m], bh[n], acc[m][n], 0, 0, 0);

        // drain NEXT-tile prefetch (issued ~48 MFMAs ago), then flip buffers
        asm volatile("s_waitcnt vmcnt(0)" ::: "memory");
        asm volatile("s_barrier" ::: "memory");
    }
#undef STAGE

    // ---- fused epilogue: P[row][e] = relu(acc + b1) @ W2slice, 3-pass split ----
    // h_hi -> smem[0,16K), h_lo -> smem[16K,32K)  (A buffers, loop is done)
    float bcol[4];
    #pragma unroll
    for (int fn = 0; fn < 4; ++fn) bcol[fn] = bias[col0g + wn + fn * 16 + l15];

    f32x4 plog[2];
    plog[0] = (f32x4){0.f, 0.f, 0.f, 0.f};
    plog[1] = (f32x4){0.f, 0.f, 0.f, 0.f};

    #pragma unroll
    for (int ch = 0; ch < 2; ++ch) {
        if ((wave & 1) == ch) {
            #pragma unroll
            for (int fm = 0; fm < 4; ++fm)
                #pragma unroll
                for (int r = 0; r < 4; ++r) {
                    int row = wm + fm * 16 + l4 * 4 + r;
                    int rx = (row & 7) << 4;
                    #pragma unroll
                    for (int fn = 0; fn < 4; ++fn) {
                        float hv = fmaxf(acc[fm][fn][r] + bcol[fn], 0.f);
                        unsigned short hh = f2bf(hv);
                        unsigned short hl = f2bf(hv - bf2f(hh));
                        int byteoff = row * 128 + ((((fn * 16 + l15) * 2)) ^ rx);
                        *reinterpret_cast<unsigned short*>(smem + byteoff) = hh;
                        *reinterpret_cast<unsigned short*>(smem + 16384 + byteoff) = hl;
                    }
                }
        }
        __syncthreads();

        #pragma unroll
        for (int fmm = 0; fmm < 2; ++fmm) {
            int rowb = wave * 32 + fmm * 16 + l15;
            int rx = (rowb & 7) << 4;
            int rowbase = rowb * 128;
            #pragma unroll
            for (int kc = 0; kc < 2; ++kc) {
                int co = kc * 64 + l4 * 16;
                s16x8 ahi = *reinterpret_cast<const s16x8*>(smem + rowbase + (co ^ rx));
                s16x8 alo = *reinterpret_cast<const s16x8*>(smem + 16384 + rowbase + (co ^ rx));
                int wb = W2T_OFS + ch * 128 + kc * 64 + l4 * 16;
                s16x8 whi = *reinterpret_cast<const s16x8*>(smem + wb + l15 * W2T_PITCH);
                s16x8 wlo = *reinterpret_cast<const s16x8*>(smem + wb + (l15 + 8) * W2T_PITCH);
                plog[fmm] = MFMA_B16(ahi, whi, plog[fmm], 0, 0, 0);
                plog[fmm] = MFMA_B16(ahi, wlo, plog[fmm], 0, 0, 0);
                plog[fmm] = MFMA_B16(alo, whi, plog[fmm], 0, 0, 0);
            }
        }
        __syncthreads();
    }

    // store partials: P rows = rb*128 + wave*32 + fmm*16 + l4*4 + r, expert = l15
    if (l15 < 8) {
        #pragma unroll
        for (int fmm = 0; fmm < 2; ++fmm) {
            int rowg = rb * 128 + wave * 32 + fmm * 16 + l4 * 4;
            #pragma unroll
            for (int r = 0; r < 4; ++r)
                Plog[((size_t)cb * 8192 + rowg + r) * E_NUM + l15] = plog[fmm][r];
        }
    }
}

// ---------------- combine: reduce partials -> softmax -> top2 -> gather ------
__global__ __launch_bounds__(256) void route_combine2_kernel(
    const float* __restrict__ Plog, const float* __restrict__ b2,
    const float* __restrict__ EO, float* __restrict__ Out, int M)
{
    const int t = blockIdx.x;
    const int tid = threadIdx.x;

    __shared__ float s_logit[E_NUM];
    __shared__ float s_g[2];
    __shared__ int   s_e[2];

    if (tid < 64) {
        int cbi = tid >> 3, e = tid & 7;
        float v = Plog[((size_t)cbi * M + t) * E_NUM + e];
        v += __shfl_xor(v, 8, 64);
        v += __shfl_xor(v, 16, 64);
        v += __shfl_xor(v, 32, 64);
        if (tid < 8) s_logit[tid] = v + b2[tid];
    }
    __syncthreads();

    if (tid == 0) {
        float logits[E_NUM];
        #pragma unroll
        for (int e = 0; e < E_NUM; ++e) logits[e] = s_logit[e];
        float m = logits[0];
        #pragma unroll
        for (int e = 1; e < E_NUM; ++e) m = fmaxf(m, logits[e]);
        float p[E_NUM], ssum = 0.f;
        #pragma unroll
        for (int e = 0; e < E_NUM; ++e) { p[e] = expf(logits[e] - m); ssum += p[e]; }
        float inv = 1.f / ssum;
        #pragma unroll
        for (int e = 0; e < E_NUM; ++e) p[e] *= inv;
        int e0 = 0;
        #pragma unroll
        for (int e = 1; e < E_NUM; ++e) if (p[e] > p[e0]) e0 = e;
        int e1 = (e0 == 0) ? 1 : 0;
        #pragma unroll
        for (int e = 0; e < E_NUM; ++e)
            if (e != e0 && e != e1 && p[e] > p[e1]) e1 = e;
        s_g[0] = p[e0]; s_g[1] = p[e1];
        s_e[0] = e0;    s_e[1] = e1;
    }
    __syncthreads();

    const float g0 = s_g[0], g1 = s_g[1];
    const size_t base0 = ((size_t)s_e[0] * M + t) * H_DIM;
    const size_t base1 = ((size_t)s_e[1] * M + t) * H_DIM;
    const int d = tid * 4;
    float4 x0 = *reinterpret_cast<const float4*>(&EO[base0 + d]);
    float4 x1 = *reinterpret_cast<const float4*>(&EO[base1 + d]);
    float4 o;
    o.x = g0 * x0.x + g1 * x1.x;
    o.y = g0 * x0.y + g1 * x1.y;
    o.z = g0 * x0.z + g1 * x1.z;
    o.w = g0 * x0.w + g1 * x1.w;
    *reinterpret_cast<float4*>(&Out[(size_t)t * H_DIM + d]) = o;
}

// ---------------- R1 fallback fp32 SGEMM + old combine (verified) ----------------
#define BM 128
#define BN 128
#define BK 16
#define PAD_LD 132

__global__ __launch_bounds__(256) void gemm1_relu_kernel(
    const float* __restrict__ A, const float* __restrict__ W,
    const float* __restrict__ bias, float* __restrict__ Hout,
    int M, int N, int K)
{
    __shared__ float As[BK][PAD_LD];
    __shared__ float Bs[BK][PAD_LD];
    const int tid = threadIdx.x;
    const int tx = tid & 15;
    const int ty = tid >> 4;
    const int row0 = blockIdx.y * BM;
    const int col0 = blockIdx.x * BN;
    float acc[8][8];
    #pragma unroll
    for (int i = 0; i < 8; ++i)
        #pragma unroll
        for (int j = 0; j < 8; ++j) acc[i][j] = 0.f;
    const int a_row = tid >> 2;
    const int a_k4  = (tid & 3) * 4;
    const int b_col4 = (tid & 31) * 4;
    const int b_kk   = tid >> 5;
    for (int k0 = 0; k0 < K; k0 += BK) {
        #pragma unroll
        for (int half = 0; half < 2; ++half) {
            int r = a_row + half * 64;
            float4 av = *reinterpret_cast<const float4*>(&A[(size_t)(row0 + r) * K + k0 + a_k4]);
            As[a_k4 + 0][r] = av.x; As[a_k4 + 1][r] = av.y;
            As[a_k4 + 2][r] = av.z; As[a_k4 + 3][r] = av.w;
        }
        #pragma unroll
        for (int half = 0; half < 2; ++half) {
            int kk = b_kk + half * 8;
            float4 bv = *reinterpret_cast<const float4*>(&W[(size_t)(k0 + kk) * N + col0 + b_col4]);
            *reinterpret_cast<float4*>(&Bs[kk][b_col4]) = bv;
        }
        __syncthreads();
        #pragma unroll
        for (int k = 0; k < BK; ++k) {
            float4 a0 = *reinterpret_cast<const float4*>(&As[k][ty * 8]);
            float4 a1 = *reinterpret_cast<const float4*>(&As[k][ty * 8 + 4]);
            float4 b0 = *reinterpret_cast<const float4*>(&Bs[k][tx * 8]);
            float4 b1 = *reinterpret_cast<const float4*>(&Bs[k][tx * 8 + 4]);
            float a[8] = {a0.x, a0.y, a0.z, a0.w, a1.x, a1.y, a1.z, a1.w};
            float b[8] = {b0.x, b0.y, b0.z, b0.w, b1.x, b1.y, b1.z, b1.w};
            #pragma unroll
            for (int i = 0; i < 8; ++i)
                #pragma unroll
                for (int j = 0; j < 8; ++j)
                    acc[i][j] = fmaf(a[i], b[j], acc[i][j]);
        }
        __syncthreads();
    }
    #pragma unroll
    for (int i = 0; i < 8; ++i) {
        int row = row0 + ty * 8 + i;
        #pragma unroll
        for (int j4 = 0; j4 < 2; ++j4) {
            int col = col0 + tx * 8 + j4 * 4;
            float4 v;
            v.x = fmaxf(acc[i][j4 * 4 + 0] + bias[col + 0], 0.f);
            v.y = fmaxf(acc[i][j4 * 4 + 1] + bias[col + 1], 0.f);
            v.z = fmaxf(acc[i][j4 * 4 + 2] + bias[col + 2], 0.f);
            v.w = fmaxf(acc[i][j4 * 4 + 3] + bias[col + 3], 0.f);
            *reinterpret_cast<float4*>(&Hout[(size_t)row * N + col]) = v;
        }
    }
}

__global__ __launch_bounds__(256) void route_combine_kernel(
    const float* __restrict__ Hbuf, const float* __restrict__ W2,
    const float* __restrict__ b2, const float* __restrict__ EO,
    float* __restrict__ Out, int M)
{
    const int t = blockIdx.x;
    const int tid = threadIdx.x;
    const int lane = tid & 63;
    const int wave = tid >> 6;
    const float* hrow = Hbuf + (size_t)t * H_DIM;

    float part[E_NUM];
    #pragma unroll
    for (int e = 0; e < E_NUM; ++e) part[e] = 0.f;
    #pragma unroll
    for (int it = 0; it < H_DIM / 256; ++it) {
        int j = tid + it * 256;
        float hv = hrow[j];
        const float* w = W2 + (size_t)j * E_NUM;
        #pragma unroll
        for (int e = 0; e < E_NUM; ++e) part[e] = fmaf(hv, w[e], part[e]);
    }
    #pragma unroll
    for (int off = 32; off > 0; off >>= 1)
        #pragma unroll
        for (int e = 0; e < E_NUM; ++e)
            part[e] += __shfl_down(part[e], off, 64);

    __shared__ float sred[4][E_NUM];
    __shared__ float s_g[2];
    __shared__ int   s_e[2];
    if (lane == 0)
        #pragma unroll
        for (int e = 0; e < E_NUM; ++e) sred[wave][e] = part[e];
    __syncthreads();

    if (tid == 0) {
        float logits[E_NUM];
        #pragma unroll
        for (int e = 0; e < E_NUM; ++e)
            logits[e] = sred[0][e] + sred[1][e] + sred[2][e] + sred[3][e] + b2[e];
        float m = logits[0];
        #pragma unroll
        for (int e = 1; e < E_NUM; ++e) m = fmaxf(m, logits[e]);
        float p[E_NUM], ssum = 0.f;
        #pragma unroll
        for (int e = 0; e < E_NUM; ++e) { p[e] = expf(logits[e] - m); ssum += p[e]; }
        float inv = 1.f / ssum;
        #pragma unroll
        for (int e = 0; e < E_NUM; ++e) p[e] *= inv;
        int e0 = 0;
        #pragma unroll
        for (int e = 1; e < E_NUM; ++e) if (p[e] > p[e0]) e0 = e;
        int e1 = (e0 == 0) ? 1 : 0;
        #pragma unroll
        for (int e = 0; e < E_NUM; ++e)
            if (e != e0 && e != e1 && p[e] > p[e1]) e1 = e;
        s_g[0] = p[e0]; s_g[1] = p[e1];
        s_e[0] = e0;    s_e[1] = e1;
    }
    __syncthreads();

    const float g0 = s_g[0], g1 = s_g[1];
    const size_t base0 = ((size_t)s_e[0] * M + t) * H_DIM;
    const size_t base1 = ((size_t)s_e[1] * M + t) * H_DIM;
    const int d = tid * 4;
    float4 x0 = *reinterpret_cast<const float4*>(&EO[base0 + d]);
    float4 x1 = *reinterpret_cast<const float4*>(&EO[base1 + d]);
    float4 o;
    o.x = g0 * x0.x + g1 * x1.x;
    o.y = g0 * x0.y + g1 * x1.y;
    o.z = g0 * x0.z + g1 * x1.z;
    o.w = g0 * x0.w + g1 * x1.w;
    *reinterpret_cast<float4*>(&Out[(size_t)t * H_DIM + d]) = o;
}

extern "C" void kernel_launch(void* const* d_in, const int* in_sizes, int n_in,
                              void* d_out, int out_size, void* d_ws, size_t ws_size,
                              hipStream_t stream)
{
    const float* hs = (const float*)d_in[0];
    const float* EO = (const float*)d_in[1];
    const float* W1 = (const float*)d_in[2];
    const float* b1 = (const float*)d_in[3];
    const float* W2 = (const float*)d_in[4];
    const float* b2 = (const float*)d_in[5];

    const int M = in_sizes[0] / H_DIM;   // 8192
    float* out = (float*)d_out;

    const size_t A_IMG = (size_t)64 * 32 * 16384;       // 33,554,432
    const size_t B_IMG = (size_t)8 * 32 * 16384;        //  4,194,304
    const size_t PART  = (size_t)8 * 8192 * 8 * 4;      //  2,097,152
    if (M == 8192 && ws_size >= A_IMG + B_IMG + PART) {
        char*  Aimg = (char*)d_ws;
        char*  Bimg = (char*)d_ws + A_IMG;
        float* Plog = (float*)((char*)d_ws + A_IMG + B_IMG);
        prep_fused_kernel<<<4096 + 512, 256, 0, stream>>>(hs, W1, Aimg, Bimg);
        gemm1_logits_kernel<<<512, 256, 0, stream>>>(Aimg, Bimg, b1, W2, Plog);
        route_combine2_kernel<<<M, 256, 0, stream>>>(Plog, b2, EO, out, M);
    } else {
        dim3 grid1(H_DIM / BN, M / BM);
        gemm1_relu_kernel<<<grid1, 256, 0, stream>>>(hs, W1, b1, out, M, H_DIM, H_DIM);
        route_combine_kernel<<<M, 256, 0, stream>>>(out, W2, b2, EO, out, M);
    }
}

// Round 10
// 85.941 us; speedup vs baseline: 2.1080x; 1.0052x over previous
//
#include <hip/hip_runtime.h>
#include <math.h>

// ExpertGating: h=relu(hs@W1+b1); logits=h@W2+b2; softmax; top-2; combine.
// R10: faithful 8-phase-template port of GEMM1 (split-bf16 3-pass):
//  256x128 tile, 8 waves (4m x 2n, 64x64/wave), BK=32, 256 blocks = 1/CU,
//  TRIPLE-buffered LDS (A 3x32K, B 3x16K) -> counted s_waitcnt vmcnt(6) at
//  iteration top (issue-to-wait = 2 iterations), 3 fine phases per K-tile:
//  {ds_read group || 2 gload issues; barrier; lgkmcnt(0); sched_barrier;
//   setprio(1); 16 MFMA; setprio(0); barrier}. Logits epilogue (verified R6)
//  extended to 256 rows. prep + combine kernels unchanged (verified).

#define H_DIM 1024
#define E_NUM 8

typedef __attribute__((ext_vector_type(8))) short s16x8;
typedef __attribute__((ext_vector_type(8))) unsigned short u16x8;
typedef __attribute__((ext_vector_type(4))) float f32x4;

__device__ __forceinline__ unsigned short f2bf(float x) {
    unsigned int u = __float_as_uint(x);
    unsigned int r = (u + 0x7FFFu + ((u >> 16) & 1u)) >> 16;
    return (unsigned short)r;
}
__device__ __forceinline__ float bf2f(unsigned short b) {
    return __uint_as_float(((unsigned int)b) << 16);
}
__device__ __forceinline__ void gload_lds16(const void* g, void* lds) {
    __builtin_amdgcn_global_load_lds(
        (const __attribute__((address_space(1))) void*)g,
        (__attribute__((address_space(3))) void*)lds, 16, 0, 0);
}

// ---------------- fused prep: hs and W1 -> swizzled hi/lo bf16 images --------
// Image tile = 128 rows x 128 B (8 slots of 16B: slots 0-3 hi k-octets, 4-7 lo),
// logical slot s stored at physical slot s ^ (row&7).
__global__ __launch_bounds__(256) void prep_fused_kernel(
    const float* __restrict__ A, const float* __restrict__ W,
    char* __restrict__ Aimg, char* __restrict__ Bimg)
{
    if (blockIdx.x < 4096) {
        int t = blockIdx.x * 256 + threadIdx.x;   // 8192 rows x 128 octets
        int m = t >> 7;
        int k = (t & 127) << 3;
        const float* src = A + ((size_t)m << 10) + k;
        float4 v0 = *reinterpret_cast<const float4*>(src);
        float4 v1 = *reinterpret_cast<const float4*>(src + 4);
        float xs[8] = {v0.x, v0.y, v0.z, v0.w, v1.x, v1.y, v1.z, v1.w};
        u16x8 hv, lv;
        #pragma unroll
        for (int j = 0; j < 8; ++j) {
            unsigned short h = f2bf(xs[j]);
            hv[j] = h;
            lv[j] = f2bf(xs[j] - bf2f(h));
        }
        int rb = m >> 7, mr = m & 127, kt = k >> 5, s = (k >> 3) & 3;
        char* base = Aimg + (((size_t)(rb * 32 + kt)) << 14) + mr * 128;
        *reinterpret_cast<u16x8*>(base + ((s ^ (mr & 7)) << 4)) = hv;
        *reinterpret_cast<u16x8*>(base + (((s + 4) ^ (mr & 7)) << 4)) = lv;
    } else {
        int t = (blockIdx.x - 4096) * 256 + threadIdx.x;  // 1024 cols x 128 octets
        int n = t & 1023;
        int k = (t >> 10) << 3;
        u16x8 hv, lv;
        #pragma unroll
        for (int j = 0; j < 8; ++j) {
            float x = W[((size_t)(k + j) << 10) + n];
            unsigned short h = f2bf(x);
            hv[j] = h;
            lv[j] = f2bf(x - bf2f(h));
        }
        int cb = n >> 7, nr = n & 127, kt = k >> 5, s = (k >> 3) & 3;
        char* base = Bimg + (((size_t)(cb * 32 + kt)) << 14) + nr * 128;
        *reinterpret_cast<u16x8*>(base + ((s ^ (nr & 7)) << 4)) = hv;
        *reinterpret_cast<u16x8*>(base + (((s + 4) ^ (nr & 7)) << 4)) = lv;
    }
}

// ---------------- GEMM1 256x128 8-phase + fused router logits ----------------
// LDS: A bufs 3x32K @0/32K/64K; B bufs 3x16K @96K/112K/128K; w2t @144K(147456).
// Epilogue reuses [0,32K)=h_hi[256][64-per-half], [32K,64K)=h_lo.
#define MFMA_B16 __builtin_amdgcn_mfma_f32_16x16x32_bf16
#define W2T_OFS 147456
#define W2T_PITCH 272

__global__ __launch_bounds__(512, 2) void gemm1_logits_kernel(
    const char* __restrict__ Aimg, const char* __restrict__ Bimg,
    const float* __restrict__ bias, const float* __restrict__ W2,
    float* __restrict__ Plog)
{
    __shared__ char smem[153984];

    const int bid = blockIdx.x;
    const int swz = (bid & 7) * 32 + (bid >> 3);   // bijective, 256 % 8 == 0
    const int rb2 = swz >> 3;    // 0..31 (rows rb2*256..+255)
    const int cb  = swz & 7;     // 0..7  (cols cb*128..+127)

    const int tid = threadIdx.x;
    const int lane = tid & 63;
    const int wave = tid >> 6;           // 0..7
    const int wm = (wave >> 1) * 64;     // 0,64,128,192
    const int wn = (wave & 1) * 64;      // 0,64
    const int l15 = lane & 15, l4 = lane >> 4;
    const int toff = tid << 4;           // 0..8191

    // ---- w2t: zero, then fill hi/lo bf16 of W2 slice (transposed) ----
    const int col0g = cb * 128;
    for (int i = tid; i < 1632; i += 512)
        *reinterpret_cast<float*>(smem + W2T_OFS + i * 4) = 0.f;
    __syncthreads();
    {
        int e = tid & 7, c2 = tid >> 3;   // c2: 0..63
        #pragma unroll
        for (int j = 0; j < 2; ++j) {
            int col = c2 * 2 + j;
            float w = W2[(size_t)(col0g + col) * E_NUM + e];
            unsigned short wh = f2bf(w);
            unsigned short wl = f2bf(w - bf2f(wh));
            *reinterpret_cast<unsigned short*>(smem + W2T_OFS + e * W2T_PITCH + col * 2) = wh;
            *reinterpret_cast<unsigned short*>(smem + W2T_OFS + (e + 8) * W2T_PITCH + col * 2) = wl;
        }
    }
    __syncthreads();

    // fragment LDS offsets (buffer-relative, swizzle baked in)
    int aoff_h[4], aoff_l[4], boff_h[4], boff_l[4];
    #pragma unroll
    for (int f = 0; f < 4; ++f) {
        int ar = wm + f * 16 + l15;                 // 0..255
        int sub = (ar >> 7) << 14;
        int arr = (ar & 127) * 128;
        int arx = ar & 7;
        aoff_h[f] = sub + arr + ((l4 ^ arx) << 4);
        aoff_l[f] = sub + arr + (((l4 + 4) ^ arx) << 4);
        int br = wn + f * 16 + l15;                 // 0..127
        int brx = br & 7;
        boff_h[f] = br * 128 + ((l4 ^ brx) << 4);
        boff_l[f] = br * 128 + (((l4 + 4) ^ brx) << 4);
    }

    const size_t atb = (size_t)(rb2 * 2) * 32;   // A image tile-index base

#define GA(s_, kt_) (Aimg + ((atb + (size_t)(s_) * 32 + (kt_)) << 14))
#define GB(kt_)     (Bimg + (((size_t)cb * 32 + (kt_)) << 14))
#define STAGE_A(kt_, s_, bO) do { const char* g_ = GA(s_, kt_);              \
    gload_lds16(g_ + toff,        smem + (bO) + (s_) * 16384 + toff);        \
    gload_lds16(g_ + 8192 + toff, smem + (bO) + (s_) * 16384 + 8192 + toff); \
} while (0)
#define STAGE_B(kt_, bO) do { const char* g_ = GB(kt_);                      \
    gload_lds16(g_ + toff,        smem + (bO) + toff);                       \
    gload_lds16(g_ + 8192 + toff, smem + (bO) + 8192 + toff);                \
} while (0)

    f32x4 acc[4][4];
    #pragma unroll
    for (int i = 0; i < 4; ++i)
        #pragma unroll
        for (int j = 0; j < 4; ++j)
            acc[i][j] = (f32x4){0.f, 0.f, 0.f, 0.f};

    // prologue: tiles 0,1 -> buffers 0,1 (12 loads outstanding)
    STAGE_A(0, 0, 0);      STAGE_A(0, 1, 0);      STAGE_B(0, 98304);
    STAGE_A(1, 0, 32768);  STAGE_A(1, 1, 32768);  STAGE_B(1, 98304 + 16384);

    int bi = 0;   // t % 3
    for (int t = 0; t < 32; ++t) {
        const char* As = smem + bi * 32768;
        const char* Bs = smem + 98304 + bi * 16384;
        int pi = bi + 2; if (pi >= 3) pi -= 3;          // (t+2) % 3
        const int pA = pi * 32768;
        const int pB = 98304 + pi * 16384;

        // counted wait: oldest 6 (tile t) done; tile t+1's 6 stay in flight
        if (t < 31) asm volatile("s_waitcnt vmcnt(6)" ::: "memory");
        else        asm volatile("s_waitcnt vmcnt(0)" ::: "memory");
        __builtin_amdgcn_s_barrier();

        // ---- P0: read A-hi + B-hi; stage A-sub0(t+2); MFMA pass hh ----
        s16x8 ah[4], bh[4];
        #pragma unroll
        for (int f = 0; f < 4; ++f) {
            ah[f] = *reinterpret_cast<const s16x8*>(As + aoff_h[f]);
            bh[f] = *reinterpret_cast<const s16x8*>(Bs + boff_h[f]);
        }
        if (t < 30) STAGE_A(t + 2, 0, pA);
        __builtin_amdgcn_s_barrier();
        asm volatile("s_waitcnt lgkmcnt(0)" ::: "memory");
        __builtin_amdgcn_sched_barrier(0);
        __builtin_amdgcn_s_setprio(1);
        #pragma unroll
        for (int m = 0; m < 4; ++m)
            #pragma unroll
            for (int n = 0; n < 4; ++n)
                acc[m][n] = MFMA_B16(ah[m], bh[n], acc[m][n], 0, 0, 0);
        __builtin_amdgcn_s_setprio(0);
        __builtin_amdgcn_s_barrier();

        // ---- P1: read B-lo; stage A-sub1(t+2); MFMA pass hl ----
        s16x8 bl[4];
        #pragma unroll
        for (int f = 0; f < 4; ++f)
            bl[f] = *reinterpret_cast<const s16x8*>(Bs + boff_l[f]);
        if (t < 30) STAGE_A(t + 2, 1, pA);
        __builtin_amdgcn_s_barrier();
        asm volatile("s_waitcnt lgkmcnt(0)" ::: "memory");
        __builtin_amdgcn_sched_barrier(0);
        __builtin_amdgcn_s_setprio(1);
        #pragma unroll
        for (int m = 0; m < 4; ++m)
            #pragma unroll
            for (int n = 0; n < 4; ++n)
                acc[m][n] = MFMA_B16(ah[m], bl[n], acc[m][n], 0, 0, 0);
        __builtin_amdgcn_s_setprio(0);
        __builtin_amdgcn_s_barrier();

        // ---- P2: read A-lo; stage B(t+2); MFMA pass lh ----
        s16x8 al[4];
        #pragma unroll
        for (int f = 0; f < 4; ++f)
            al[f] = *reinterpret_cast<const s16x8*>(As + aoff_l[f]);
        if (t < 30) STAGE_B(t + 2, pB);
        __builtin_amdgcn_s_barrier();
        asm volatile("s_waitcnt lgkmcnt(0)" ::: "memory");
        __builtin_amdgcn_sched_barrier(0);
        __builtin_amdgcn_s_setprio(1);
        #pragma unroll
        for (int m = 0; m < 4; ++m)
            #pragma unroll
            for (int n = 0; n < 4; ++n)
                acc[m][n] = MFMA_B16(al[m], bh[n], acc[m][n], 0, 0, 0);
        __builtin_amdgcn_s_setprio(0);
        __builtin_amdgcn_s_barrier();

        bi = bi + 1; if (bi >= 3) bi = 0;
    }
#undef STAGE_A
#undef STAGE_B
#undef GA
#undef GB

    // ---- fused epilogue: P[row][e] = relu(acc + b1) @ W2slice, 3-pass split --
    // h_hi -> smem[0,32K), h_lo -> smem[32K,64K)  (A buffers, loop done)
    float bcol[4];
    #pragma unroll
    for (int fn = 0; fn < 4; ++fn) bcol[fn] = bias[col0g + wn + fn * 16 + l15];

    f32x4 plog[2];
    plog[0] = (f32x4){0.f, 0.f, 0.f, 0.f};
    plog[1] = (f32x4){0.f, 0.f, 0.f, 0.f};

    #pragma unroll
    for (int ch = 0; ch < 2; ++ch) {
        // waves owning col-half ch write h hi/lo (swizzled); rows 0..255
        if ((wave & 1) == ch) {
            #pragma unroll
            for (int fm = 0; fm < 4; ++fm)
                #pragma unroll
                for (int r = 0; r < 4; ++r) {
                    int row = wm + fm * 16 + l4 * 4 + r;
                    int rx = (row & 7) << 4;
                    #pragma unroll
                    for (int fn = 0; fn < 4; ++fn) {
                        float hv = fmaxf(acc[fm][fn][r] + bcol[fn], 0.f);
                        unsigned short hh = f2bf(hv);
                        unsigned short hl = f2bf(hv - bf2f(hh));
                        int byteoff = row * 128 + ((((fn * 16 + l15) * 2)) ^ rx);
                        *reinterpret_cast<unsigned short*>(smem + byteoff) = hh;
                        *reinterpret_cast<unsigned short*>(smem + 32768 + byteoff) = hl;
                    }
                }
        }
        __syncthreads();

        // all waves: logits MFMA over this 64-col half (16 row-groups of 16)
        #pragma unroll
        for (int fmm = 0; fmm < 2; ++fmm) {
            int rowb = wave * 32 + fmm * 16 + l15;   // 0..255
            int rx = (rowb & 7) << 4;
            int rowbase = rowb * 128;
            #pragma unroll
            for (int kc = 0; kc < 2; ++kc) {
                int co = kc * 64 + l4 * 16;
                s16x8 ahi = *reinterpret_cast<const s16x8*>(smem + rowbase + (co ^ rx));
                s16x8 alo = *reinterpret_cast<const s16x8*>(smem + 32768 + rowbase + (co ^ rx));
                int wb = W2T_OFS + ch * 128 + kc * 64 + l4 * 16;
                s16x8 whi = *reinterpret_cast<const s16x8*>(smem + wb + l15 * W2T_PITCH);
                s16x8 wlo = *reinterpret_cast<const s16x8*>(smem + wb + (l15 + 8) * W2T_PITCH);
                plog[fmm] = MFMA_B16(ahi, whi, plog[fmm], 0, 0, 0);
                plog[fmm] = MFMA_B16(ahi, wlo, plog[fmm], 0, 0, 0);
                plog[fmm] = MFMA_B16(alo, whi, plog[fmm], 0, 0, 0);
            }
        }
        __syncthreads();
    }

    // store partials: rows = rb2*256 + wave*32 + fmm*16 + l4*4 + r, expert = l15
    if (l15 < 8) {
        #pragma unroll
        for (int fmm = 0; fmm < 2; ++fmm) {
            int rowg = rb2 * 256 + wave * 32 + fmm * 16 + l4 * 4;
            #pragma unroll
            for (int r = 0; r < 4; ++r)
                Plog[((size_t)cb * 8192 + rowg + r) * E_NUM + l15] = plog[fmm][r];
        }
    }
}

// ---------------- combine: reduce partials -> softmax -> top2 -> gather ------
__global__ __launch_bounds__(256) void route_combine2_kernel(
    const float* __restrict__ Plog, const float* __restrict__ b2,
    const float* __restrict__ EO, float* __restrict__ Out, int M)
{
    const int t = blockIdx.x;
    const int tid = threadIdx.x;

    __shared__ float s_logit[E_NUM];
    __shared__ float s_g[2];
    __shared__ int   s_e[2];

    if (tid < 64) {
        int cbi = tid >> 3, e = tid & 7;
        float v = Plog[((size_t)cbi * M + t) * E_NUM + e];
        v += __shfl_xor(v, 8, 64);
        v += __shfl_xor(v, 16, 64);
        v += __shfl_xor(v, 32, 64);
        if (tid < 8) s_logit[tid] = v + b2[tid];
    }
    __syncthreads();

    if (tid == 0) {
        float logits[E_NUM];
        #pragma unroll
        for (int e = 0; e < E_NUM; ++e) logits[e] = s_logit[e];
        float m = logits[0];
        #pragma unroll
        for (int e = 1; e < E_NUM; ++e) m = fmaxf(m, logits[e]);
        float p[E_NUM], ssum = 0.f;
        #pragma unroll
        for (int e = 0; e < E_NUM; ++e) { p[e] = expf(logits[e] - m); ssum += p[e]; }
        float inv = 1.f / ssum;
        #pragma unroll
        for (int e = 0; e < E_NUM; ++e) p[e] *= inv;
        int e0 = 0;
        #pragma unroll
        for (int e = 1; e < E_NUM; ++e) if (p[e] > p[e0]) e0 = e;
        int e1 = (e0 == 0) ? 1 : 0;
        #pragma unroll
        for (int e = 0; e < E_NUM; ++e)
            if (e != e0 && e != e1 && p[e] > p[e1]) e1 = e;
        s_g[0] = p[e0]; s_g[1] = p[e1];
        s_e[0] = e0;    s_e[1] = e1;
    }
    __syncthreads();

    const float g0 = s_g[0], g1 = s_g[1];
    const size_t base0 = ((size_t)s_e[0] * M + t) * H_DIM;
    const size_t base1 = ((size_t)s_e[1] * M + t) * H_DIM;
    const int d = tid * 4;
    float4 x0 = *reinterpret_cast<const float4*>(&EO[base0 + d]);
    float4 x1 = *reinterpret_cast<const float4*>(&EO[base1 + d]);
    float4 o;
    o.x = g0 * x0.x + g1 * x1.x;
    o.y = g0 * x0.y + g1 * x1.y;
    o.z = g0 * x0.z + g1 * x1.z;
    o.w = g0 * x0.w + g1 * x1.w;
    *reinterpret_cast<float4*>(&Out[(size_t)t * H_DIM + d]) = o;
}

// ---------------- R1 fallback fp32 SGEMM + old combine (verified) ----------------
#define BM 128
#define BN 128
#define BK 16
#define PAD_LD 132

__global__ __launch_bounds__(256) void gemm1_relu_kernel(
    const float* __restrict__ A, const float* __restrict__ W,
    const float* __restrict__ bias, float* __restrict__ Hout,
    int M, int N, int K)
{
    __shared__ float As[BK][PAD_LD];
    __shared__ float Bs[BK][PAD_LD];
    const int tid = threadIdx.x;
    const int tx = tid & 15;
    const int ty = tid >> 4;
    const int row0 = blockIdx.y * BM;
    const int col0 = blockIdx.x * BN;
    float acc[8][8];
    #pragma unroll
    for (int i = 0; i < 8; ++i)
        #pragma unroll
        for (int j = 0; j < 8; ++j) acc[i][j] = 0.f;
    const int a_row = tid >> 2;
    const int a_k4  = (tid & 3) * 4;
    const int b_col4 = (tid & 31) * 4;
    const int b_kk   = tid >> 5;
    for (int k0 = 0; k0 < K; k0 += BK) {
        #pragma unroll
        for (int half = 0; half < 2; ++half) {
            int r = a_row + half * 64;
            float4 av = *reinterpret_cast<const float4*>(&A[(size_t)(row0 + r) * K + k0 + a_k4]);
            As[a_k4 + 0][r] = av.x; As[a_k4 + 1][r] = av.y;
            As[a_k4 + 2][r] = av.z; As[a_k4 + 3][r] = av.w;
        }
        #pragma unroll
        for (int half = 0; half < 2; ++half) {
            int kk = b_kk + half * 8;
            float4 bv = *reinterpret_cast<const float4*>(&W[(size_t)(k0 + kk) * N + col0 + b_col4]);
            *reinterpret_cast<float4*>(&Bs[kk][b_col4]) = bv;
        }
        __syncthreads();
        #pragma unroll
        for (int k = 0; k < BK; ++k) {
            float4 a0 = *reinterpret_cast<const float4*>(&As[k][ty * 8]);
            float4 a1 = *reinterpret_cast<const float4*>(&As[k][ty * 8 + 4]);
            float4 b0 = *reinterpret_cast<const float4*>(&Bs[k][tx * 8]);
            float4 b1 = *reinterpret_cast<const float4*>(&Bs[k][tx * 8 + 4]);
            float a[8] = {a0.x, a0.y, a0.z, a0.w, a1.x, a1.y, a1.z, a1.w};
            float b[8] = {b0.x, b0.y, b0.z, b0.w, b1.x, b1.y, b1.z, b1.w};
            #pragma unroll
            for (int i = 0; i < 8; ++i)
                #pragma unroll
                for (int j = 0; j < 8; ++j)
                    acc[i][j] = fmaf(a[i], b[j], acc[i][j]);
        }
        __syncthreads();
    }
    #pragma unroll
    for (int i = 0; i < 8; ++i) {
        int row = row0 + ty * 8 + i;
        #pragma unroll
        for (int j4 = 0; j4 < 2; ++j4) {
            int col = col0 + tx * 8 + j4 * 4;
            float4 v;
            v.x = fmaxf(acc[i][j4 * 4 + 0] + bias[col + 0], 0.f);
            v.y = fmaxf(acc[i][j4 * 4 + 1] + bias[col + 1], 0.f);
            v.z = fmaxf(acc[i][j4 * 4 + 2] + bias[col + 2], 0.f);
            v.w = fmaxf(acc[i][j4 * 4 + 3] + bias[col + 3], 0.f);
            *reinterpret_cast<float4*>(&Hout[(size_t)row * N + col]) = v;
        }
    }
}

__global__ __launch_bounds__(256) void route_combine_kernel(
    const float* __restrict__ Hbuf, const float* __restrict__ W2,
    const float* __restrict__ b2, const float* __restrict__ EO,
    float* __restrict__ Out, int M)
{
    const int t = blockIdx.x;
    const int tid = threadIdx.x;
    const int lane = tid & 63;
    const int wave = tid >> 6;
    const float* hrow = Hbuf + (size_t)t * H_DIM;

    float part[E_NUM];
    #pragma unroll
    for (int e = 0; e < E_NUM; ++e) part[e] = 0.f;
    #pragma unroll
    for (int it = 0; it < H_DIM / 256; ++it) {
        int j = tid + it * 256;
        float hv = hrow[j];
        const float* w = W2 + (size_t)j * E_NUM;
        #pragma unroll
        for (int e = 0; e < E_NUM; ++e) part[e] = fmaf(hv, w[e], part[e]);
    }
    #pragma unroll
    for (int off = 32; off > 0; off >>= 1)
        #pragma unroll
        for (int e = 0; e < E_NUM; ++e)
            part[e] += __shfl_down(part[e], off, 64);

    __shared__ float sred[4][E_NUM];
    __shared__ float s_g[2];
    __shared__ int   s_e[2];
    if (lane == 0)
        #pragma unroll
        for (int e = 0; e < E_NUM; ++e) sred[wave][e] = part[e];
    __syncthreads();

    if (tid == 0) {
        float logits[E_NUM];
        #pragma unroll
        for (int e = 0; e < E_NUM; ++e)
            logits[e] = sred[0][e] + sred[1][e] + sred[2][e] + sred[3][e] + b2[e];
        float m = logits[0];
        #pragma unroll
        for (int e = 1; e < E_NUM; ++e) m = fmaxf(m, logits[e]);
        float p[E_NUM], ssum = 0.f;
        #pragma unroll
        for (int e = 0; e < E_NUM; ++e) { p[e] = expf(logits[e] - m); ssum += p[e]; }
        float inv = 1.f / ssum;
        #pragma unroll
        for (int e = 0; e < E_NUM; ++e) p[e] *= inv;
        int e0 = 0;
        #pragma unroll
        for (int e = 1; e < E_NUM; ++e) if (p[e] > p[e0]) e0 = e;
        int e1 = (e0 == 0) ? 1 : 0;
        #pragma unroll
        for (int e = 0; e < E_NUM; ++e)
            if (e != e0 && e != e1 && p[e] > p[e1]) e1 = e;
        s_g[0] = p[e0]; s_g[1] = p[e1];
        s_e[0] = e0;    s_e[1] = e1;
    }
    __syncthreads();

    const float g0 = s_g[0], g1 = s_g[1];
    const size_t base0 = ((size_t)s_e[0] * M + t) * H_DIM;
    const size_t base1 = ((size_t)s_e[1] * M + t) * H_DIM;
    const int d = tid * 4;
    float4 x0 = *reinterpret_cast<const float4*>(&EO[base0 + d]);
    float4 x1 = *reinterpret_cast<const float4*>(&EO[base1 + d]);
    float4 o;
    o.x = g0 * x0.x + g1 * x1.x;
    o.y = g0 * x0.y + g1 * x1.y;
    o.z = g0 * x0.z + g1 * x1.z;
    o.w = g0 * x0.w + g1 * x1.w;
    *reinterpret_cast<float4*>(&Out[(size_t)t * H_DIM + d]) = o;
}

extern "C" void kernel_launch(void* const* d_in, const int* in_sizes, int n_in,
                              void* d_out, int out_size, void* d_ws, size_t ws_size,
                              hipStream_t stream)
{
    const float* hs = (const float*)d_in[0];
    const float* EO = (const float*)d_in[1];
    const float* W1 = (const float*)d_in[2];
    const float* b1 = (const float*)d_in[3];
    const float* W2 = (const float*)d_in[4];
    const float* b2 = (const float*)d_in[5];

    const int M = in_sizes[0] / H_DIM;   // 8192
    float* out = (float*)d_out;

    const size_t A_IMG = (size_t)64 * 32 * 16384;       // 33,554,432
    const size_t B_IMG = (size_t)8 * 32 * 16384;        //  4,194,304
    const size_t PART  = (size_t)8 * 8192 * 8 * 4;      //  2,097,152
    if (M == 8192 && ws_size >= A_IMG + B_IMG + PART) {
        char*  Aimg = (char*)d_ws;
        char*  Bimg = (char*)d_ws + A_IMG;
        float* Plog = (float*)((char*)d_ws + A_IMG + B_IMG);
        prep_fused_kernel<<<4096 + 512, 256, 0, stream>>>(hs, W1, Aimg, Bimg);
        gemm1_logits_kernel<<<256, 512, 0, stream>>>(Aimg, Bimg, b1, W2, Plog);
        route_combine2_kernel<<<M, 256, 0, stream>>>(Plog, b2, EO, out, M);
    } else {
        dim3 grid1(H_DIM / BN, M / BM);
        gemm1_relu_kernel<<<grid1, 256, 0, stream>>>(hs, W1, b1, out, M, H_DIM, H_DIM);
        route_combine_kernel<<<M, 256, 0, stream>>>(out, W2, b2, EO, out, M);
    }
}

// Round 11
// 85.342 us; speedup vs baseline: 2.1228x; 1.0070x over previous
//
#include <hip/hip_runtime.h>
#include <math.h>

// ExpertGating: h=relu(hs@W1+b1); logits=h@W2+b2; softmax; top-2; combine.
// R11: R6 kernel with the ONE correct counted-vmcnt pattern (T3/T4):
//   top of iter kt: STAGE(kt+1 -> other buf); s_waitcnt vmcnt(8)  <- waits only
//   tile-kt's loads (issued one full iteration ago, ~free); barrier; ds_read+
//   48 MFMA on cur buf; barrier. Never drains next to its own issue (R9's bug).
// LDS: A dbuf 2x16K @0/16K, B dbuf @32K/48K, w2t @64K (70.5KB, 2 blocks/CU =
// grid cap, unchanged from R6). Everything else identical to verified R6.

#define H_DIM 1024
#define E_NUM 8

typedef __attribute__((ext_vector_type(8))) short s16x8;
typedef __attribute__((ext_vector_type(8))) unsigned short u16x8;
typedef __attribute__((ext_vector_type(4))) float f32x4;

__device__ __forceinline__ unsigned short f2bf(float x) {
    unsigned int u = __float_as_uint(x);
    unsigned int r = (u + 0x7FFFu + ((u >> 16) & 1u)) >> 16;
    return (unsigned short)r;
}
__device__ __forceinline__ float bf2f(unsigned short b) {
    return __uint_as_float(((unsigned int)b) << 16);
}
__device__ __forceinline__ void gload_lds16(const void* g, void* lds) {
    __builtin_amdgcn_global_load_lds(
        (const __attribute__((address_space(1))) void*)g,
        (__attribute__((address_space(3))) void*)lds, 16, 0, 0);
}

// ---------------- fused prep: hs and W1 -> swizzled hi/lo bf16 images --------
__global__ __launch_bounds__(256) void prep_fused_kernel(
    const float* __restrict__ A, const float* __restrict__ W,
    char* __restrict__ Aimg, char* __restrict__ Bimg)
{
    if (blockIdx.x < 4096) {
        int t = blockIdx.x * 256 + threadIdx.x;   // 8192 rows x 128 octets
        int m = t >> 7;
        int k = (t & 127) << 3;
        const float* src = A + ((size_t)m << 10) + k;
        float4 v0 = *reinterpret_cast<const float4*>(src);
        float4 v1 = *reinterpret_cast<const float4*>(src + 4);
        float xs[8] = {v0.x, v0.y, v0.z, v0.w, v1.x, v1.y, v1.z, v1.w};
        u16x8 hv, lv;
        #pragma unroll
        for (int j = 0; j < 8; ++j) {
            unsigned short h = f2bf(xs[j]);
            hv[j] = h;
            lv[j] = f2bf(xs[j] - bf2f(h));
        }
        int rb = m >> 7, mr = m & 127, kt = k >> 5, s = (k >> 3) & 3;
        char* base = Aimg + (((size_t)(rb * 32 + kt)) << 14) + mr * 128;
        *reinterpret_cast<u16x8*>(base + ((s ^ (mr & 7)) << 4)) = hv;
        *reinterpret_cast<u16x8*>(base + (((s + 4) ^ (mr & 7)) << 4)) = lv;
    } else {
        int t = (blockIdx.x - 4096) * 256 + threadIdx.x;  // 1024 cols x 128 octets
        int n = t & 1023;
        int k = (t >> 10) << 3;
        u16x8 hv, lv;
        #pragma unroll
        for (int j = 0; j < 8; ++j) {
            float x = W[((size_t)(k + j) << 10) + n];
            unsigned short h = f2bf(x);
            hv[j] = h;
            lv[j] = f2bf(x - bf2f(h));
        }
        int cb = n >> 7, nr = n & 127, kt = k >> 5, s = (k >> 3) & 3;
        char* base = Bimg + (((size_t)(cb * 32 + kt)) << 14) + nr * 128;
        *reinterpret_cast<u16x8*>(base + ((s ^ (nr & 7)) << 4)) = hv;
        *reinterpret_cast<u16x8*>(base + (((s + 4) ^ (nr & 7)) << 4)) = lv;
    }
}

// ---------------- GEMM1 + fused router logits, counted-vmcnt dbuf ----------
// LDS: A0 [0,16K) A1 [16K,32K) B0 [32K,48K) B1 [48K,64K) w2t [64K,70.4K)
// Epilogue reuses A0 = h_hi[128][64], A1 = h_lo[128][64].
#define MFMA_B16 __builtin_amdgcn_mfma_f32_16x16x32_bf16
#define W2T_OFS 65536
#define W2T_PITCH 272

__global__ __launch_bounds__(256, 2) void gemm1_logits_kernel(
    const char* __restrict__ Aimg, const char* __restrict__ Bimg,
    const float* __restrict__ bias, const float* __restrict__ W2,
    float* __restrict__ Plog)
{
    __shared__ char smem[72064];

    int bid = blockIdx.x;
    int swz = (bid & 7) * 64 + (bid >> 3);   // bijective, 512 % 8 == 0
    int rb = swz >> 3;          // 0..63
    int cb = swz & 7;           // 0..7

    int tid = threadIdx.x;
    int lane = tid & 63;
    int wave = tid >> 6;
    int wm = (wave >> 1) * 64;
    int wn = (wave & 1) * 64;
    int l15 = lane & 15, l4 = lane >> 4;

    // ---- w2t: zero, then fill hi/lo bf16 of W2 slice (transposed) ----
    const int col0g = cb * 128;
    for (int i = tid; i < 1632; i += 256)
        *reinterpret_cast<float*>(smem + W2T_OFS + i * 4) = 0.f;
    __syncthreads();
    {
        int e = tid & 7, c4 = tid >> 3;   // c4: 0..31
        #pragma unroll
        for (int j = 0; j < 4; ++j) {
            int col = c4 * 4 + j;
            float w = W2[(size_t)(col0g + col) * E_NUM + e];
            unsigned short wh = f2bf(w);
            unsigned short wl = f2bf(w - bf2f(wh));
            *reinterpret_cast<unsigned short*>(smem + W2T_OFS + e * W2T_PITCH + col * 2) = wh;
            *reinterpret_cast<unsigned short*>(smem + W2T_OFS + (e + 8) * W2T_PITCH + col * 2) = wl;
        }
    }
    __syncthreads();

    // fragment LDS offsets (buffer-relative, swizzle baked in)
    int aoff_h[4], aoff_l[4], boff_h[4], boff_l[4];
    #pragma unroll
    for (int f = 0; f < 4; ++f) {
        int ar = wm + f * 16 + l15;
        aoff_h[f] = ar * 128 + ((l4 ^ (ar & 7)) << 4);
        aoff_l[f] = ar * 128 + (((l4 + 4) ^ (ar & 7)) << 4);
        int br = wn + f * 16 + l15;
        boff_h[f] = br * 128 + ((l4 ^ (br & 7)) << 4);
        boff_l[f] = br * 128 + (((l4 + 4) ^ (br & 7)) << 4);
    }

    const char* abase = Aimg + (size_t)rb * (32 * 16384);
    const char* bbase = Bimg + (size_t)cb * (32 * 16384);
    const int toff = tid << 4;

#define STAGE(kt_, aO, bO) do {                                              \
    const char* ga_ = abase + (((size_t)(kt_)) << 14);                       \
    const char* gb_ = bbase + (((size_t)(kt_)) << 14);                       \
    gload_lds16(ga_ + toff,         smem + (aO) + toff);                     \
    gload_lds16(ga_ + 4096 + toff,  smem + (aO) + 4096 + toff);              \
    gload_lds16(ga_ + 8192 + toff,  smem + (aO) + 8192 + toff);              \
    gload_lds16(ga_ + 12288 + toff, smem + (aO) + 12288 + toff);             \
    gload_lds16(gb_ + toff,         smem + (bO) + toff);                     \
    gload_lds16(gb_ + 4096 + toff,  smem + (bO) + 4096 + toff);              \
    gload_lds16(gb_ + 8192 + toff,  smem + (bO) + 8192 + toff);              \
    gload_lds16(gb_ + 12288 + toff, smem + (bO) + 12288 + toff);             \
} while (0)

    f32x4 acc[4][4];
    #pragma unroll
    for (int i = 0; i < 4; ++i)
        #pragma unroll
        for (int j = 0; j < 4; ++j)
            acc[i][j] = (f32x4){0.f, 0.f, 0.f, 0.f};

    // prologue: tile 0 -> buffer 0 (8 loads in flight)
    STAGE(0, 0, 32768);

    for (int kt = 0; kt < 32; ++kt) {
        const int cur = kt & 1;
        const char* As = smem + cur * 16384;
        const char* Bs = smem + 32768 + cur * 16384;

        // issue next tile FIRST, then counted-wait for the CURRENT tile whose
        // loads were issued one full iteration ago (~free wait)
        if (kt < 31) {
            STAGE(kt + 1, (cur ^ 1) * 16384, 32768 + (cur ^ 1) * 16384);
            asm volatile("s_waitcnt vmcnt(8)" ::: "memory");  // tile kt landed
        } else {
            asm volatile("s_waitcnt vmcnt(0)" ::: "memory");
        }
        asm volatile("s_barrier" ::: "memory");   // all waves: tile kt ready

        s16x8 ah[4], al[4], bh[4], bl[4];
        #pragma unroll
        for (int f = 0; f < 4; ++f) {
            ah[f] = *reinterpret_cast<const s16x8*>(As + aoff_h[f]);
            al[f] = *reinterpret_cast<const s16x8*>(As + aoff_l[f]);
            bh[f] = *reinterpret_cast<const s16x8*>(Bs + boff_h[f]);
            bl[f] = *reinterpret_cast<const s16x8*>(Bs + boff_l[f]);
        }
        #pragma unroll
        for (int m = 0; m < 4; ++m)
            #pragma unroll
            for (int n = 0; n < 4; ++n)
                acc[m][n] = MFMA_B16(ah[m], bh[n], acc[m][n], 0, 0, 0);
        #pragma unroll
        for (int m = 0; m < 4; ++m)
            #pragma unroll
            for (int n = 0; n < 4; ++n)
                acc[m][n] = MFMA_B16(ah[m], bl[n], acc[m][n], 0, 0, 0);
        #pragma unroll
        for (int m = 0; m < 4; ++m)
            #pragma unroll
            for (int n = 0; n < 4; ++n)
                acc[m][n] = MFMA_B16(al[m], bh[n], acc[m][n], 0, 0, 0);

        // all waves done reading cur before next iter's STAGE overwrites it
        asm volatile("s_barrier" ::: "memory");
    }
#undef STAGE

    // ---- fused epilogue: P[row][e] = relu(acc + b1) @ W2slice, 3-pass split ----
    float bcol[4];
    #pragma unroll
    for (int fn = 0; fn < 4; ++fn) bcol[fn] = bias[col0g + wn + fn * 16 + l15];

    f32x4 plog[2];
    plog[0] = (f32x4){0.f, 0.f, 0.f, 0.f};
    plog[1] = (f32x4){0.f, 0.f, 0.f, 0.f};

    #pragma unroll
    for (int ch = 0; ch < 2; ++ch) {
        if ((wave & 1) == ch) {
            #pragma unroll
            for (int fm = 0; fm < 4; ++fm)
                #pragma unroll
                for (int r = 0; r < 4; ++r) {
                    int row = wm + fm * 16 + l4 * 4 + r;
                    int rx = (row & 7) << 4;
                    #pragma unroll
                    for (int fn = 0; fn < 4; ++fn) {
                        float hv = fmaxf(acc[fm][fn][r] + bcol[fn], 0.f);
                        unsigned short hh = f2bf(hv);
                        unsigned short hl = f2bf(hv - bf2f(hh));
                        int byteoff = row * 128 + ((((fn * 16 + l15) * 2)) ^ rx);
                        *reinterpret_cast<unsigned short*>(smem + byteoff) = hh;
                        *reinterpret_cast<unsigned short*>(smem + 16384 + byteoff) = hl;
                    }
                }
        }
        __syncthreads();

        #pragma unroll
        for (int fmm = 0; fmm < 2; ++fmm) {
            int rowb = wave * 32 + fmm * 16 + l15;
            int rx = (rowb & 7) << 4;
            int rowbase = rowb * 128;
            #pragma unroll
            for (int kc = 0; kc < 2; ++kc) {
                int co = kc * 64 + l4 * 16;
                s16x8 ahi = *reinterpret_cast<const s16x8*>(smem + rowbase + (co ^ rx));
                s16x8 alo = *reinterpret_cast<const s16x8*>(smem + 16384 + rowbase + (co ^ rx));
                int wb = W2T_OFS + ch * 128 + kc * 64 + l4 * 16;
                s16x8 whi = *reinterpret_cast<const s16x8*>(smem + wb + l15 * W2T_PITCH);
                s16x8 wlo = *reinterpret_cast<const s16x8*>(smem + wb + (l15 + 8) * W2T_PITCH);
                plog[fmm] = MFMA_B16(ahi, whi, plog[fmm], 0, 0, 0);
                plog[fmm] = MFMA_B16(ahi, wlo, plog[fmm], 0, 0, 0);
                plog[fmm] = MFMA_B16(alo, whi, plog[fmm], 0, 0, 0);
            }
        }
        __syncthreads();
    }

    // store partials: P rows = rb*128 + wave*32 + fmm*16 + l4*4 + r, expert = l15
    if (l15 < 8) {
        #pragma unroll
        for (int fmm = 0; fmm < 2; ++fmm) {
            int rowg = rb * 128 + wave * 32 + fmm * 16 + l4 * 4;
            #pragma unroll
            for (int r = 0; r < 4; ++r)
                Plog[((size_t)cb * 8192 + rowg + r) * E_NUM + l15] = plog[fmm][r];
        }
    }
}

// ---------------- combine: reduce partials -> softmax -> top2 -> gather ------
__global__ __launch_bounds__(256) void route_combine2_kernel(
    const float* __restrict__ Plog, const float* __restrict__ b2,
    const float* __restrict__ EO, float* __restrict__ Out, int M)
{
    const int t = blockIdx.x;
    const int tid = threadIdx.x;

    __shared__ float s_logit[E_NUM];
    __shared__ float s_g[2];
    __shared__ int   s_e[2];

    if (tid < 64) {
        int cbi = tid >> 3, e = tid & 7;
        float v = Plog[((size_t)cbi * M + t) * E_NUM + e];
        v += __shfl_xor(v, 8, 64);
        v += __shfl_xor(v, 16, 64);
        v += __shfl_xor(v, 32, 64);
        if (tid < 8) s_logit[tid] = v + b2[tid];
    }
    __syncthreads();

    if (tid == 0) {
        float logits[E_NUM];
        #pragma unroll
        for (int e = 0; e < E_NUM; ++e) logits[e] = s_logit[e];
        float m = logits[0];
        #pragma unroll
        for (int e = 1; e < E_NUM; ++e) m = fmaxf(m, logits[e]);
        float p[E_NUM], ssum = 0.f;
        #pragma unroll
        for (int e = 0; e < E_NUM; ++e) { p[e] = expf(logits[e] - m); ssum += p[e]; }
        float inv = 1.f / ssum;
        #pragma unroll
        for (int e = 0; e < E_NUM; ++e) p[e] *= inv;
        int e0 = 0;
        #pragma unroll
        for (int e = 1; e < E_NUM; ++e) if (p[e] > p[e0]) e0 = e;
        int e1 = (e0 == 0) ? 1 : 0;
        #pragma unroll
        for (int e = 0; e < E_NUM; ++e)
            if (e != e0 && e != e1 && p[e] > p[e1]) e1 = e;
        s_g[0] = p[e0]; s_g[1] = p[e1];
        s_e[0] = e0;    s_e[1] = e1;
    }
    __syncthreads();

    const float g0 = s_g[0], g1 = s_g[1];
    const size_t base0 = ((size_t)s_e[0] * M + t) * H_DIM;
    const size_t base1 = ((size_t)s_e[1] * M + t) * H_DIM;
    const int d = tid * 4;
    float4 x0 = *reinterpret_cast<const float4*>(&EO[base0 + d]);
    float4 x1 = *reinterpret_cast<const float4*>(&EO[base1 + d]);
    float4 o;
    o.x = g0 * x0.x + g1 * x1.x;
    o.y = g0 * x0.y + g1 * x1.y;
    o.z = g0 * x0.z + g1 * x1.z;
    o.w = g0 * x0.w + g1 * x1.w;
    *reinterpret_cast<float4*>(&Out[(size_t)t * H_DIM + d]) = o;
}

// ---------------- R1 fallback fp32 SGEMM + old combine (verified) ----------------
#define BM 128
#define BN 128
#define BK 16
#define PAD_LD 132

__global__ __launch_bounds__(256) void gemm1_relu_kernel(
    const float* __restrict__ A, const float* __restrict__ W,
    const float* __restrict__ bias, float* __restrict__ Hout,
    int M, int N, int K)
{
    __shared__ float As[BK][PAD_LD];
    __shared__ float Bs[BK][PAD_LD];
    const int tid = threadIdx.x;
    const int tx = tid & 15;
    const int ty = tid >> 4;
    const int row0 = blockIdx.y * BM;
    const int col0 = blockIdx.x * BN;
    float acc[8][8];
    #pragma unroll
    for (int i = 0; i < 8; ++i)
        #pragma unroll
        for (int j = 0; j < 8; ++j) acc[i][j] = 0.f;
    const int a_row = tid >> 2;
    const int a_k4  = (tid & 3) * 4;
    const int b_col4 = (tid & 31) * 4;
    const int b_kk   = tid >> 5;
    for (int k0 = 0; k0 < K; k0 += BK) {
        #pragma unroll
        for (int half = 0; half < 2; ++half) {
            int r = a_row + half * 64;
            float4 av = *reinterpret_cast<const float4*>(&A[(size_t)(row0 + r) * K + k0 + a_k4]);
            As[a_k4 + 0][r] = av.x; As[a_k4 + 1][r] = av.y;
            As[a_k4 + 2][r] = av.z; As[a_k4 + 3][r] = av.w;
        }
        #pragma unroll
        for (int half = 0; half < 2; ++half) {
            int kk = b_kk + half * 8;
            float4 bv = *reinterpret_cast<const float4*>(&W[(size_t)(k0 + kk) * N + col0 + b_col4]);
            *reinterpret_cast<float4*>(&Bs[kk][b_col4]) = bv;
        }
        __syncthreads();
        #pragma unroll
        for (int k = 0; k < BK; ++k) {
            float4 a0 = *reinterpret_cast<const float4*>(&As[k][ty * 8]);
            float4 a1 = *reinterpret_cast<const float4*>(&As[k][ty * 8 + 4]);
            float4 b0 = *reinterpret_cast<const float4*>(&Bs[k][tx * 8]);
            float4 b1 = *reinterpret_cast<const float4*>(&Bs[k][tx * 8 + 4]);
            float a[8] = {a0.x, a0.y, a0.z, a0.w, a1.x, a1.y, a1.z, a1.w};
            float b[8] = {b0.x, b0.y, b0.z, b0.w, b1.x, b1.y, b1.z, b1.w};
            #pragma unroll
            for (int i = 0; i < 8; ++i)
                #pragma unroll
                for (int j = 0; j < 8; ++j)
                    acc[i][j] = fmaf(a[i], b[j], acc[i][j]);
        }
        __syncthreads();
    }
    #pragma unroll
    for (int i = 0; i < 8; ++i) {
        int row = row0 + ty * 8 + i;
        #pragma unroll
        for (int j4 = 0; j4 < 2; ++j4) {
            int col = col0 + tx * 8 + j4 * 4;
            float4 v;
            v.x = fmaxf(acc[i][j4 * 4 + 0] + bias[col + 0], 0.f);
            v.y = fmaxf(acc[i][j4 * 4 + 1] + bias[col + 1], 0.f);
            v.z = fmaxf(acc[i][j4 * 4 + 2] + bias[col + 2], 0.f);
            v.w = fmaxf(acc[i][j4 * 4 + 3] + bias[col + 3], 0.f);
            *reinterpret_cast<float4*>(&Hout[(size_t)row * N + col]) = v;
        }
    }
}

__global__ __launch_bounds__(256) void route_combine_kernel(
    const float* __restrict__ Hbuf, const float* __restrict__ W2,
    const float* __restrict__ b2, const float* __restrict__ EO,
    float* __restrict__ Out, int M)
{
    const int t = blockIdx.x;
    const int tid = threadIdx.x;
    const int lane = tid & 63;
    const int wave = tid >> 6;
    const float* hrow = Hbuf + (size_t)t * H_DIM;

    float part[E_NUM];
    #pragma unroll
    for (int e = 0; e < E_NUM; ++e) part[e] = 0.f;
    #pragma unroll
    for (int it = 0; it < H_DIM / 256; ++it) {
        int j = tid + it * 256;
        float hv = hrow[j];
        const float* w = W2 + (size_t)j * E_NUM;
        #pragma unroll
        for (int e = 0; e < E_NUM; ++e) part[e] = fmaf(hv, w[e], part[e]);
    }
    #pragma unroll
    for (int off = 32; off > 0; off >>= 1)
        #pragma unroll
        for (int e = 0; e < E_NUM; ++e)
            part[e] += __shfl_down(part[e], off, 64);

    __shared__ float sred[4][E_NUM];
    __shared__ float s_g[2];
    __shared__ int   s_e[2];
    if (lane == 0)
        #pragma unroll
        for (int e = 0; e < E_NUM; ++e) sred[wave][e] = part[e];
    __syncthreads();

    if (tid == 0) {
        float logits[E_NUM];
        #pragma unroll
        for (int e = 0; e < E_NUM; ++e)
            logits[e] = sred[0][e] + sred[1][e] + sred[2][e] + sred[3][e] + b2[e];
        float m = logits[0];
        #pragma unroll
        for (int e = 1; e < E_NUM; ++e) m = fmaxf(m, logits[e]);
        float p[E_NUM], ssum = 0.f;
        #pragma unroll
        for (int e = 0; e < E_NUM; ++e) { p[e] = expf(logits[e] - m); ssum += p[e]; }
        float inv = 1.f / ssum;
        #pragma unroll
        for (int e = 0; e < E_NUM; ++e) p[e] *= inv;
        int e0 = 0;
        #pragma unroll
        for (int e = 1; e < E_NUM; ++e) if (p[e] > p[e0]) e0 = e;
        int e1 = (e0 == 0) ? 1 : 0;
        #pragma unroll
        for (int e = 0; e < E_NUM; ++e)
            if (e != e0 && e != e1 && p[e] > p[e1]) e1 = e;
        s_g[0] = p[e0]; s_g[1] = p[e1];
        s_e[0] = e0;    s_e[1] = e1;
    }
    __syncthreads();

    const float g0 = s_g[0], g1 = s_g[1];
    const size_t base0 = ((size_t)s_e[0] * M + t) * H_DIM;
    const size_t base1 = ((size_t)s_e[1] * M + t) * H_DIM;
    const int d = tid * 4;
    float4 x0 = *reinterpret_cast<const float4*>(&EO[base0 + d]);
    float4 x1 = *reinterpret_cast<const float4*>(&EO[base1 + d]);
    float4 o;
    o.x = g0 * x0.x + g1 * x1.x;
    o.y = g0 * x0.y + g1 * x1.y;
    o.z = g0 * x0.z + g1 * x1.z;
    o.w = g0 * x0.w + g1 * x1.w;
    *reinterpret_cast<float4*>(&Out[(size_t)t * H_DIM + d]) = o;
}

extern "C" void kernel_launch(void* const* d_in, const int* in_sizes, int n_in,
                              void* d_out, int out_size, void* d_ws, size_t ws_size,
                              hipStream_t stream)
{
    const float* hs = (const float*)d_in[0];
    const float* EO = (const float*)d_in[1];
    const float* W1 = (const float*)d_in[2];
    const float* b1 = (const float*)d_in[3];
    const float* W2 = (const float*)d_in[4];
    const float* b2 = (const float*)d_in[5];

    const int M = in_sizes[0] / H_DIM;   // 8192
    float* out = (float*)d_out;

    const size_t A_IMG = (size_t)64 * 32 * 16384;       // 33,554,432
    const size_t B_IMG = (size_t)8 * 32 * 16384;        //  4,194,304
    const size_t PART  = (size_t)8 * 8192 * 8 * 4;      //  2,097,152
    if (M == 8192 && ws_size >= A_IMG + B_IMG + PART) {
        char*  Aimg = (char*)d_ws;
        char*  Bimg = (char*)d_ws + A_IMG;
        float* Plog = (float*)((char*)d_ws + A_IMG + B_IMG);
        prep_fused_kernel<<<4096 + 512, 256, 0, stream>>>(hs, W1, Aimg, Bimg);
        gemm1_logits_kernel<<<512, 256, 0, stream>>>(Aimg, Bimg, b1, W2, Plog);
        route_combine2_kernel<<<M, 256, 0, stream>>>(Plog, b2, EO, out, M);
    } else {
        dim3 grid1(H_DIM / BN, M / BM);
        gemm1_relu_kernel<<<grid1, 256, 0, stream>>>(hs, W1, b1, out, M, H_DIM, H_DIM);
        route_combine_kernel<<<M, 256, 0, stream>>>(out, W2, b2, EO, out, M);
    }
}

// Round 12
// 83.362 us; speedup vs baseline: 2.1732x; 1.0237x over previous
//
#include <hip/hip_runtime.h>
#include <math.h>

// ExpertGating: h=relu(hs@W1+b1); logits=h@W2+b2; softmax; top-2; combine.
// R12 = R6 (verified best, 82.5us), restored after five schedule experiments
// (R4/R8/R9/R10/R11) all regressed vs this structure:
//  - fused prep: hs,W1 -> pre-swizzled hi/lo bf16 images in ws (split-bf16,
//    3-pass MFMA keeps router logits selection-exact; error ~2^-18 rel)
//  - GEMM1: 128x128 tile, 4 waves, BK=32, global_load_lds(16B) staging,
//    XOR-swizzled ds_read_b128 fragments, 48 MFMA/kt, 2-barrier loop
//    (implicit wave-level TLP at 3 blocks/CU is the winning schedule here)
//  - fused epilogue: h -> LDS (bf16 hi/lo) -> 24 MFMA router logits partials
//    (h is never materialized to HBM)
//  - combine: 8192 blocks reduce 8 partials, softmax, top-2, gather EO.

#define H_DIM 1024
#define E_NUM 8

typedef __attribute__((ext_vector_type(8))) short s16x8;
typedef __attribute__((ext_vector_type(8))) unsigned short u16x8;
typedef __attribute__((ext_vector_type(4))) float f32x4;

__device__ __forceinline__ unsigned short f2bf(float x) {
    unsigned int u = __float_as_uint(x);
    unsigned int r = (u + 0x7FFFu + ((u >> 16) & 1u)) >> 16;
    return (unsigned short)r;
}
__device__ __forceinline__ float bf2f(unsigned short b) {
    return __uint_as_float(((unsigned int)b) << 16);
}
__device__ __forceinline__ void gload_lds16(const void* g, void* lds) {
    __builtin_amdgcn_global_load_lds(
        (const __attribute__((address_space(1))) void*)g,
        (__attribute__((address_space(3))) void*)lds, 16, 0, 0);
}

// ---------------- fused prep: hs and W1 -> swizzled hi/lo bf16 images --------
__global__ __launch_bounds__(256) void prep_fused_kernel(
    const float* __restrict__ A, const float* __restrict__ W,
    char* __restrict__ Aimg, char* __restrict__ Bimg)
{
    if (blockIdx.x < 4096) {
        int t = blockIdx.x * 256 + threadIdx.x;   // 8192 rows x 128 octets
        int m = t >> 7;
        int k = (t & 127) << 3;
        const float* src = A + ((size_t)m << 10) + k;
        float4 v0 = *reinterpret_cast<const float4*>(src);
        float4 v1 = *reinterpret_cast<const float4*>(src + 4);
        float xs[8] = {v0.x, v0.y, v0.z, v0.w, v1.x, v1.y, v1.z, v1.w};
        u16x8 hv, lv;
        #pragma unroll
        for (int j = 0; j < 8; ++j) {
            unsigned short h = f2bf(xs[j]);
            hv[j] = h;
            lv[j] = f2bf(xs[j] - bf2f(h));
        }
        int rb = m >> 7, mr = m & 127, kt = k >> 5, s = (k >> 3) & 3;
        char* base = Aimg + (((size_t)(rb * 32 + kt)) << 14) + mr * 128;
        *reinterpret_cast<u16x8*>(base + ((s ^ (mr & 7)) << 4)) = hv;
        *reinterpret_cast<u16x8*>(base + (((s + 4) ^ (mr & 7)) << 4)) = lv;
    } else {
        int t = (blockIdx.x - 4096) * 256 + threadIdx.x;  // 1024 cols x 128 octets
        int n = t & 1023;
        int k = (t >> 10) << 3;
        u16x8 hv, lv;
        #pragma unroll
        for (int j = 0; j < 8; ++j) {
            float x = W[((size_t)(k + j) << 10) + n];
            unsigned short h = f2bf(x);
            hv[j] = h;
            lv[j] = f2bf(x - bf2f(h));
        }
        int cb = n >> 7, nr = n & 127, kt = k >> 5, s = (k >> 3) & 3;
        char* base = Bimg + (((size_t)(cb * 32 + kt)) << 14) + nr * 128;
        *reinterpret_cast<u16x8*>(base + ((s ^ (nr & 7)) << 4)) = hv;
        *reinterpret_cast<u16x8*>(base + (((s + 4) ^ (nr & 7)) << 4)) = lv;
    }
}

// ---------------- GEMM1 + fused router logits ----------------
// LDS map: [0,16384)=As / h_hi[128][64]; [16384,32768)=Bs / h_lo[128][64];
//          [32768,39296)=w2t 24 rows x 272B (rows 0-7 hi, 8-15 lo, 16-23 zero)
#define MFMA_B16 __builtin_amdgcn_mfma_f32_16x16x32_bf16
#define W2T_OFS 32768
#define W2T_PITCH 272

__global__ __launch_bounds__(256, 3) void gemm1_logits_kernel(
    const char* __restrict__ Aimg, const char* __restrict__ Bimg,
    const float* __restrict__ bias, const float* __restrict__ W2,
    float* __restrict__ Plog)
{
    __shared__ char smem[39296];

    int bid = blockIdx.x;
    int swz = (bid & 7) * 64 + (bid >> 3);   // bijective, 512 % 8 == 0
    int rb = swz >> 3;          // 0..63
    int cb = swz & 7;           // 0..7

    int tid = threadIdx.x;
    int lane = tid & 63;
    int wave = tid >> 6;
    int wm = (wave >> 1) * 64;
    int wn = (wave & 1) * 64;
    int l15 = lane & 15, l4 = lane >> 4;

    // ---- w2t: zero, then fill hi/lo bf16 of W2 slice (transposed) ----
    const int col0g = cb * 128;
    for (int i = tid; i < 1632; i += 256)
        *reinterpret_cast<float*>(smem + W2T_OFS + i * 4) = 0.f;
    __syncthreads();
    {
        int e = tid & 7, c4 = tid >> 3;   // c4: 0..31
        #pragma unroll
        for (int j = 0; j < 4; ++j) {
            int col = c4 * 4 + j;
            float w = W2[(size_t)(col0g + col) * E_NUM + e];
            unsigned short wh = f2bf(w);
            unsigned short wl = f2bf(w - bf2f(wh));
            *reinterpret_cast<unsigned short*>(smem + W2T_OFS + e * W2T_PITCH + col * 2) = wh;
            *reinterpret_cast<unsigned short*>(smem + W2T_OFS + (e + 8) * W2T_PITCH + col * 2) = wl;
        }
    }
    __syncthreads();

    // fragment LDS offsets (swizzle baked in), constant across K-tiles
    int aoff_h[4], aoff_l[4], boff_h[4], boff_l[4];
    #pragma unroll
    for (int f = 0; f < 4; ++f) {
        int ar = wm + f * 16 + l15;
        aoff_h[f] = ar * 128 + ((l4 ^ (ar & 7)) << 4);
        aoff_l[f] = ar * 128 + (((l4 + 4) ^ (ar & 7)) << 4);
        int br = wn + f * 16 + l15;
        boff_h[f] = 16384 + br * 128 + ((l4 ^ (br & 7)) << 4);
        boff_l[f] = 16384 + br * 128 + (((l4 + 4) ^ (br & 7)) << 4);
    }

    const char* abase = Aimg + (size_t)rb * (32 * 16384);
    const char* bbase = Bimg + (size_t)cb * (32 * 16384);

    f32x4 acc[4][4];
    #pragma unroll
    for (int i = 0; i < 4; ++i)
        #pragma unroll
        for (int j = 0; j < 4; ++j)
            acc[i][j] = (f32x4){0.f, 0.f, 0.f, 0.f};

    for (int kt = 0; kt < 32; ++kt) {
        const char* ga = abase + (kt << 14);
        const char* gb = bbase + (kt << 14);
        int toff = tid << 4;
        #pragma unroll
        for (int r = 0; r < 4; ++r) {
            gload_lds16(ga + (r << 12) + toff, smem + (r << 12) + toff);
            gload_lds16(gb + (r << 12) + toff, smem + 16384 + (r << 12) + toff);
        }
        __syncthreads();

        s16x8 ah[4], al[4], bh[4], bl[4];
        #pragma unroll
        for (int f = 0; f < 4; ++f) {
            ah[f] = *reinterpret_cast<const s16x8*>(smem + aoff_h[f]);
            al[f] = *reinterpret_cast<const s16x8*>(smem + aoff_l[f]);
            bh[f] = *reinterpret_cast<const s16x8*>(smem + boff_h[f]);
            bl[f] = *reinterpret_cast<const s16x8*>(smem + boff_l[f]);
        }
        #pragma unroll
        for (int m = 0; m < 4; ++m)
            #pragma unroll
            for (int n = 0; n < 4; ++n)
                acc[m][n] = MFMA_B16(ah[m], bh[n], acc[m][n], 0, 0, 0);
        #pragma unroll
        for (int m = 0; m < 4; ++m)
            #pragma unroll
            for (int n = 0; n < 4; ++n)
                acc[m][n] = MFMA_B16(ah[m], bl[n], acc[m][n], 0, 0, 0);
        #pragma unroll
        for (int m = 0; m < 4; ++m)
            #pragma unroll
            for (int n = 0; n < 4; ++n)
                acc[m][n] = MFMA_B16(al[m], bh[n], acc[m][n], 0, 0, 0);
        __syncthreads();
    }

    // ---- fused epilogue: P[row][e] = relu(acc + b1) @ W2slice, 3-pass split ----
    float bcol[4];
    #pragma unroll
    for (int fn = 0; fn < 4; ++fn) bcol[fn] = bias[col0g + wn + fn * 16 + l15];

    f32x4 plog[2];
    plog[0] = (f32x4){0.f, 0.f, 0.f, 0.f};
    plog[1] = (f32x4){0.f, 0.f, 0.f, 0.f};

    #pragma unroll
    for (int ch = 0; ch < 2; ++ch) {
        // waves owning col-half ch write h hi/lo (swizzled) into As/Bs region
        if ((wave & 1) == ch) {
            #pragma unroll
            for (int fm = 0; fm < 4; ++fm)
                #pragma unroll
                for (int r = 0; r < 4; ++r) {
                    int row = wm + fm * 16 + l4 * 4 + r;
                    int rx = (row & 7) << 4;
                    #pragma unroll
                    for (int fn = 0; fn < 4; ++fn) {
                        float hv = fmaxf(acc[fm][fn][r] + bcol[fn], 0.f);
                        unsigned short hh = f2bf(hv);
                        unsigned short hl = f2bf(hv - bf2f(hh));
                        int byteoff = row * 128 + ((((fn * 16 + l15) * 2)) ^ rx);
                        *reinterpret_cast<unsigned short*>(smem + byteoff) = hh;
                        *reinterpret_cast<unsigned short*>(smem + 16384 + byteoff) = hl;
                    }
                }
        }
        __syncthreads();

        // all waves: logits MFMA over this 64-col half (K chunks kc=0,1)
        #pragma unroll
        for (int fmm = 0; fmm < 2; ++fmm) {
            int rowb = wave * 32 + fmm * 16 + l15;
            int rx = (rowb & 7) << 4;
            int rowbase = rowb * 128;
            #pragma unroll
            for (int kc = 0; kc < 2; ++kc) {
                int co = kc * 64 + l4 * 16;
                s16x8 ahi = *reinterpret_cast<const s16x8*>(smem + rowbase + (co ^ rx));
                s16x8 alo = *reinterpret_cast<const s16x8*>(smem + 16384 + rowbase + (co ^ rx));
                int wb = W2T_OFS + ch * 128 + kc * 64 + l4 * 16;
                s16x8 whi = *reinterpret_cast<const s16x8*>(smem + wb + l15 * W2T_PITCH);
                s16x8 wlo = *reinterpret_cast<const s16x8*>(smem + wb + (l15 + 8) * W2T_PITCH);
                plog[fmm] = MFMA_B16(ahi, whi, plog[fmm], 0, 0, 0);
                plog[fmm] = MFMA_B16(ahi, wlo, plog[fmm], 0, 0, 0);
                plog[fmm] = MFMA_B16(alo, whi, plog[fmm], 0, 0, 0);
            }
        }
        __syncthreads();
    }

    // store partials: P rows = rb*128 + wave*32 + fmm*16 + l4*4 + r, expert = l15
    if (l15 < 8) {
        #pragma unroll
        for (int fmm = 0; fmm < 2; ++fmm) {
            int rowg = rb * 128 + wave * 32 + fmm * 16 + l4 * 4;
            #pragma unroll
            for (int r = 0; r < 4; ++r)
                Plog[((size_t)cb * 8192 + rowg + r) * E_NUM + l15] = plog[fmm][r];
        }
    }
}

// ---------------- combine: reduce partials -> softmax -> top2 -> gather ------
__global__ __launch_bounds__(256) void route_combine2_kernel(
    const float* __restrict__ Plog, const float* __restrict__ b2,
    const float* __restrict__ EO, float* __restrict__ Out, int M)
{
    const int t = blockIdx.x;
    const int tid = threadIdx.x;

    __shared__ float s_logit[E_NUM];
    __shared__ float s_g[2];
    __shared__ int   s_e[2];

    if (tid < 64) {
        int cbi = tid >> 3, e = tid & 7;
        float v = Plog[((size_t)cbi * M + t) * E_NUM + e];
        v += __shfl_xor(v, 8, 64);
        v += __shfl_xor(v, 16, 64);
        v += __shfl_xor(v, 32, 64);
        if (tid < 8) s_logit[tid] = v + b2[tid];
    }
    __syncthreads();

    if (tid == 0) {
        float logits[E_NUM];
        #pragma unroll
        for (int e = 0; e < E_NUM; ++e) logits[e] = s_logit[e];
        float m = logits[0];
        #pragma unroll
        for (int e = 1; e < E_NUM; ++e) m = fmaxf(m, logits[e]);
        float p[E_NUM], ssum = 0.f;
        #pragma unroll
        for (int e = 0; e < E_NUM; ++e) { p[e] = expf(logits[e] - m); ssum += p[e]; }
        float inv = 1.f / ssum;
        #pragma unroll
        for (int e = 0; e < E_NUM; ++e) p[e] *= inv;
        int e0 = 0;
        #pragma unroll
        for (int e = 1; e < E_NUM; ++e) if (p[e] > p[e0]) e0 = e;
        int e1 = (e0 == 0) ? 1 : 0;
        #pragma unroll
        for (int e = 0; e < E_NUM; ++e)
            if (e != e0 && e != e1 && p[e] > p[e1]) e1 = e;
        s_g[0] = p[e0]; s_g[1] = p[e1];
        s_e[0] = e0;    s_e[1] = e1;
    }
    __syncthreads();

    const float g0 = s_g[0], g1 = s_g[1];
    const size_t base0 = ((size_t)s_e[0] * M + t) * H_DIM;
    const size_t base1 = ((size_t)s_e[1] * M + t) * H_DIM;
    const int d = tid * 4;
    float4 x0 = *reinterpret_cast<const float4*>(&EO[base0 + d]);
    float4 x1 = *reinterpret_cast<const float4*>(&EO[base1 + d]);
    float4 o;
    o.x = g0 * x0.x + g1 * x1.x;
    o.y = g0 * x0.y + g1 * x1.y;
    o.z = g0 * x0.z + g1 * x1.z;
    o.w = g0 * x0.w + g1 * x1.w;
    *reinterpret_cast<float4*>(&Out[(size_t)t * H_DIM + d]) = o;
}

// ---------------- R1 fallback fp32 SGEMM + old combine (verified) ----------------
#define BM 128
#define BN 128
#define BK 16
#define PAD_LD 132

__global__ __launch_bounds__(256) void gemm1_relu_kernel(
    const float* __restrict__ A, const float* __restrict__ W,
    const float* __restrict__ bias, float* __restrict__ Hout,
    int M, int N, int K)
{
    __shared__ float As[BK][PAD_LD];
    __shared__ float Bs[BK][PAD_LD];
    const int tid = threadIdx.x;
    const int tx = tid & 15;
    const int ty = tid >> 4;
    const int row0 = blockIdx.y * BM;
    const int col0 = blockIdx.x * BN;
    float acc[8][8];
    #pragma unroll
    for (int i = 0; i < 8; ++i)
        #pragma unroll
        for (int j = 0; j < 8; ++j) acc[i][j] = 0.f;
    const int a_row = tid >> 2;
    const int a_k4  = (tid & 3) * 4;
    const int b_col4 = (tid & 31) * 4;
    const int b_kk   = tid >> 5;
    for (int k0 = 0; k0 < K; k0 += BK) {
        #pragma unroll
        for (int half = 0; half < 2; ++half) {
            int r = a_row + half * 64;
            float4 av = *reinterpret_cast<const float4*>(&A[(size_t)(row0 + r) * K + k0 + a_k4]);
            As[a_k4 + 0][r] = av.x; As[a_k4 + 1][r] = av.y;
            As[a_k4 + 2][r] = av.z; As[a_k4 + 3][r] = av.w;
        }
        #pragma unroll
        for (int half = 0; half < 2; ++half) {
            int kk = b_kk + half * 8;
            float4 bv = *reinterpret_cast<const float4*>(&W[(size_t)(k0 + kk) * N + col0 + b_col4]);
            *reinterpret_cast<float4*>(&Bs[kk][b_col4]) = bv;
        }
        __syncthreads();
        #pragma unroll
        for (int k = 0; k < BK; ++k) {
            float4 a0 = *reinterpret_cast<const float4*>(&As[k][ty * 8]);
            float4 a1 = *reinterpret_cast<const float4*>(&As[k][ty * 8 + 4]);
            float4 b0 = *reinterpret_cast<const float4*>(&Bs[k][tx * 8]);
            float4 b1 = *reinterpret_cast<const float4*>(&Bs[k][tx * 8 + 4]);
            float a[8] = {a0.x, a0.y, a0.z, a0.w, a1.x, a1.y, a1.z, a1.w};
            float b[8] = {b0.x, b0.y, b0.z, b0.w, b1.x, b1.y, b1.z, b1.w};
            #pragma unroll
            for (int i = 0; i < 8; ++i)
                #pragma unroll
                for (int j = 0; j < 8; ++j)
                    acc[i][j] = fmaf(a[i], b[j], acc[i][j]);
        }
        __syncthreads();
    }
    #pragma unroll
    for (int i = 0; i < 8; ++i) {
        int row = row0 + ty * 8 + i;
        #pragma unroll
        for (int j4 = 0; j4 < 2; ++j4) {
            int col = col0 + tx * 8 + j4 * 4;
            float4 v;
            v.x = fmaxf(acc[i][j4 * 4 + 0] + bias[col + 0], 0.f);
            v.y = fmaxf(acc[i][j4 * 4 + 1] + bias[col + 1], 0.f);
            v.z = fmaxf(acc[i][j4 * 4 + 2] + bias[col + 2], 0.f);
            v.w = fmaxf(acc[i][j4 * 4 + 3] + bias[col + 3], 0.f);
            *reinterpret_cast<float4*>(&Hout[(size_t)row * N + col]) = v;
        }
    }
}

__global__ __launch_bounds__(256) void route_combine_kernel(
    const float* __restrict__ Hbuf, const float* __restrict__ W2,
    const float* __restrict__ b2, const float* __restrict__ EO,
    float* __restrict__ Out, int M)
{
    const int t = blockIdx.x;
    const int tid = threadIdx.x;
    const int lane = tid & 63;
    const int wave = tid >> 6;
    const float* hrow = Hbuf + (size_t)t * H_DIM;

    float part[E_NUM];
    #pragma unroll
    for (int e = 0; e < E_NUM; ++e) part[e] = 0.f;
    #pragma unroll
    for (int it = 0; it < H_DIM / 256; ++it) {
        int j = tid + it * 256;
        float hv = hrow[j];
        const float* w = W2 + (size_t)j * E_NUM;
        #pragma unroll
        for (int e = 0; e < E_NUM; ++e) part[e] = fmaf(hv, w[e], part[e]);
    }
    #pragma unroll
    for (int off = 32; off > 0; off >>= 1)
        #pragma unroll
        for (int e = 0; e < E_NUM; ++e)
            part[e] += __shfl_down(part[e], off, 64);

    __shared__ float sred[4][E_NUM];
    __shared__ float s_g[2];
    __shared__ int   s_e[2];
    if (lane == 0)
        #pragma unroll
        for (int e = 0; e < E_NUM; ++e) sred[wave][e] = part[e];
    __syncthreads();

    if (tid == 0) {
        float logits[E_NUM];
        #pragma unroll
        for (int e = 0; e < E_NUM; ++e)
            logits[e] = sred[0][e] + sred[1][e] + sred[2][e] + sred[3][e] + b2[e];
        float m = logits[0];
        #pragma unroll
        for (int e = 1; e < E_NUM; ++e) m = fmaxf(m, logits[e]);
        float p[E_NUM], ssum = 0.f;
        #pragma unroll
        for (int e = 0; e < E_NUM; ++e) { p[e] = expf(logits[e] - m); ssum += p[e]; }
        float inv = 1.f / ssum;
        #pragma unroll
        for (int e = 0; e < E_NUM; ++e) p[e] *= inv;
        int e0 = 0;
        #pragma unroll
        for (int e = 1; e < E_NUM; ++e) if (p[e] > p[e0]) e0 = e;
        int e1 = (e0 == 0) ? 1 : 0;
        #pragma unroll
        for (int e = 0; e < E_NUM; ++e)
            if (e != e0 && e != e1 && p[e] > p[e1]) e1 = e;
        s_g[0] = p[e0]; s_g[1] = p[e1];
        s_e[0] = e0;    s_e[1] = e1;
    }
    __syncthreads();

    const float g0 = s_g[0], g1 = s_g[1];
    const size_t base0 = ((size_t)s_e[0] * M + t) * H_DIM;
    const size_t base1 = ((size_t)s_e[1] * M + t) * H_DIM;
    const int d = tid * 4;
    float4 x0 = *reinterpret_cast<const float4*>(&EO[base0 + d]);
    float4 x1 = *reinterpret_cast<const float4*>(&EO[base1 + d]);
    float4 o;
    o.x = g0 * x0.x + g1 * x1.x;
    o.y = g0 * x0.y + g1 * x1.y;
    o.z = g0 * x0.z + g1 * x1.z;
    o.w = g0 * x0.w + g1 * x1.w;
    *reinterpret_cast<float4*>(&Out[(size_t)t * H_DIM + d]) = o;
}

extern "C" void kernel_launch(void* const* d_in, const int* in_sizes, int n_in,
                              void* d_out, int out_size, void* d_ws, size_t ws_size,
                              hipStream_t stream)
{
    const float* hs = (const float*)d_in[0];
    const float* EO = (const float*)d_in[1];
    const float* W1 = (const float*)d_in[2];
    const float* b1 = (const float*)d_in[3];
    const float* W2 = (const float*)d_in[4];
    const float* b2 = (const float*)d_in[5];

    const int M = in_sizes[0] / H_DIM;   // 8192
    float* out = (float*)d_out;

    const size_t A_IMG = (size_t)64 * 32 * 16384;       // 33,554,432
    const size_t B_IMG = (size_t)8 * 32 * 16384;        //  4,194,304
    const size_t PART  = (size_t)8 * 8192 * 8 * 4;      //  2,097,152
    if (M == 8192 && ws_size >= A_IMG + B_IMG + PART) {
        char*  Aimg = (char*)d_ws;
        char*  Bimg = (char*)d_ws + A_IMG;
        float* Plog = (float*)((char*)d_ws + A_IMG + B_IMG);
        prep_fused_kernel<<<4096 + 512, 256, 0, stream>>>(hs, W1, Aimg, Bimg);
        gemm1_logits_kernel<<<512, 256, 0, stream>>>(Aimg, Bimg, b1, W2, Plog);
        route_combine2_kernel<<<M, 256, 0, stream>>>(Plog, b2, EO, out, M);
    } else {
        dim3 grid1(H_DIM / BN, M / BM);
        gemm1_relu_kernel<<<grid1, 256, 0, stream>>>(hs, W1, b1, out, M, H_DIM, H_DIM);
        route_combine_kernel<<<M, 256, 0, stream>>>(out, W2, b2, EO, out, M);
    }
}

// Round 13
// 82.295 us; speedup vs baseline: 2.2014x; 1.0130x over previous
//
#include <hip/hip_runtime.h>
#include <math.h>

// ExpertGating: h=relu(hs@W1+b1); logits=h@W2+b2; softmax; top-2; combine.
// R12 = R6 (verified best, 82.5us), restored after five schedule experiments
// (R4/R8/R9/R10/R11) all regressed vs this structure:
//  - fused prep: hs,W1 -> pre-swizzled hi/lo bf16 images in ws (split-bf16,
//    3-pass MFMA keeps router logits selection-exact; error ~2^-18 rel)
//  - GEMM1: 128x128 tile, 4 waves, BK=32, global_load_lds(16B) staging,
//    XOR-swizzled ds_read_b128 fragments, 48 MFMA/kt, 2-barrier loop
//    (implicit wave-level TLP at 3 blocks/CU is the winning schedule here)
//  - fused epilogue: h -> LDS (bf16 hi/lo) -> 24 MFMA router logits partials
//    (h is never materialized to HBM)
//  - combine: 8192 blocks reduce 8 partials, softmax, top-2, gather EO.

#define H_DIM 1024
#define E_NUM 8

typedef __attribute__((ext_vector_type(8))) short s16x8;
typedef __attribute__((ext_vector_type(8))) unsigned short u16x8;
typedef __attribute__((ext_vector_type(4))) float f32x4;

__device__ __forceinline__ unsigned short f2bf(float x) {
    unsigned int u = __float_as_uint(x);
    unsigned int r = (u + 0x7FFFu + ((u >> 16) & 1u)) >> 16;
    return (unsigned short)r;
}
__device__ __forceinline__ float bf2f(unsigned short b) {
    return __uint_as_float(((unsigned int)b) << 16);
}
__device__ __forceinline__ void gload_lds16(const void* g, void* lds) {
    __builtin_amdgcn_global_load_lds(
        (const __attribute__((address_space(1))) void*)g,
        (__attribute__((address_space(3))) void*)lds, 16, 0, 0);
}

// ---------------- fused prep: hs and W1 -> swizzled hi/lo bf16 images --------
__global__ __launch_bounds__(256) void prep_fused_kernel(
    const float* __restrict__ A, const float* __restrict__ W,
    char* __restrict__ Aimg, char* __restrict__ Bimg)
{
    if (blockIdx.x < 4096) {
        int t = blockIdx.x * 256 + threadIdx.x;   // 8192 rows x 128 octets
        int m = t >> 7;
        int k = (t & 127) << 3;
        const float* src = A + ((size_t)m << 10) + k;
        float4 v0 = *reinterpret_cast<const float4*>(src);
        float4 v1 = *reinterpret_cast<const float4*>(src + 4);
        float xs[8] = {v0.x, v0.y, v0.z, v0.w, v1.x, v1.y, v1.z, v1.w};
        u16x8 hv, lv;
        #pragma unroll
        for (int j = 0; j < 8; ++j) {
            unsigned short h = f2bf(xs[j]);
            hv[j] = h;
            lv[j] = f2bf(xs[j] - bf2f(h));
        }
        int rb = m >> 7, mr = m & 127, kt = k >> 5, s = (k >> 3) & 3;
        char* base = Aimg + (((size_t)(rb * 32 + kt)) << 14) + mr * 128;
        *reinterpret_cast<u16x8*>(base + ((s ^ (mr & 7)) << 4)) = hv;
        *reinterpret_cast<u16x8*>(base + (((s + 4) ^ (mr & 7)) << 4)) = lv;
    } else {
        int t = (blockIdx.x - 4096) * 256 + threadIdx.x;  // 1024 cols x 128 octets
        int n = t & 1023;
        int k = (t >> 10) << 3;
        u16x8 hv, lv;
        #pragma unroll
        for (int j = 0; j < 8; ++j) {
            float x = W[((size_t)(k + j) << 10) + n];
            unsigned short h = f2bf(x);
            hv[j] = h;
            lv[j] = f2bf(x - bf2f(h));
        }
        int cb = n >> 7, nr = n & 127, kt = k >> 5, s = (k >> 3) & 3;
        char* base = Bimg + (((size_t)(cb * 32 + kt)) << 14) + nr * 128;
        *reinterpret_cast<u16x8*>(base + ((s ^ (nr & 7)) << 4)) = hv;
        *reinterpret_cast<u16x8*>(base + (((s + 4) ^ (nr & 7)) << 4)) = lv;
    }
}

// ---------------- GEMM1 + fused router logits ----------------
// LDS map: [0,16384)=As / h_hi[128][64]; [16384,32768)=Bs / h_lo[128][64];
//          [32768,39296)=w2t 24 rows x 272B (rows 0-7 hi, 8-15 lo, 16-23 zero)
#define MFMA_B16 __builtin_amdgcn_mfma_f32_16x16x32_bf16
#define W2T_OFS 32768
#define W2T_PITCH 272

__global__ __launch_bounds__(256, 3) void gemm1_logits_kernel(
    const char* __restrict__ Aimg, const char* __restrict__ Bimg,
    const float* __restrict__ bias, const float* __restrict__ W2,
    float* __restrict__ Plog)
{
    __shared__ char smem[39296];

    int bid = blockIdx.x;
    int swz = (bid & 7) * 64 + (bid >> 3);   // bijective, 512 % 8 == 0
    int rb = swz >> 3;          // 0..63
    int cb = swz & 7;           // 0..7

    int tid = threadIdx.x;
    int lane = tid & 63;
    int wave = tid >> 6;
    int wm = (wave >> 1) * 64;
    int wn = (wave & 1) * 64;
    int l15 = lane & 15, l4 = lane >> 4;

    // ---- w2t: zero, then fill hi/lo bf16 of W2 slice (transposed) ----
    const int col0g = cb * 128;
    for (int i = tid; i < 1632; i += 256)
        *reinterpret_cast<float*>(smem + W2T_OFS + i * 4) = 0.f;
    __syncthreads();
    {
        int e = tid & 7, c4 = tid >> 3;   // c4: 0..31
        #pragma unroll
        for (int j = 0; j < 4; ++j) {
            int col = c4 * 4 + j;
            float w = W2[(size_t)(col0g + col) * E_NUM + e];
            unsigned short wh = f2bf(w);
            unsigned short wl = f2bf(w - bf2f(wh));
            *reinterpret_cast<unsigned short*>(smem + W2T_OFS + e * W2T_PITCH + col * 2) = wh;
            *reinterpret_cast<unsigned short*>(smem + W2T_OFS + (e + 8) * W2T_PITCH + col * 2) = wl;
        }
    }
    __syncthreads();

    // fragment LDS offsets (swizzle baked in), constant across K-tiles
    int aoff_h[4], aoff_l[4], boff_h[4], boff_l[4];
    #pragma unroll
    for (int f = 0; f < 4; ++f) {
        int ar = wm + f * 16 + l15;
        aoff_h[f] = ar * 128 + ((l4 ^ (ar & 7)) << 4);
        aoff_l[f] = ar * 128 + (((l4 + 4) ^ (ar & 7)) << 4);
        int br = wn + f * 16 + l15;
        boff_h[f] = 16384 + br * 128 + ((l4 ^ (br & 7)) << 4);
        boff_l[f] = 16384 + br * 128 + (((l4 + 4) ^ (br & 7)) << 4);
    }

    const char* abase = Aimg + (size_t)rb * (32 * 16384);
    const char* bbase = Bimg + (size_t)cb * (32 * 16384);

    f32x4 acc[4][4];
    #pragma unroll
    for (int i = 0; i < 4; ++i)
        #pragma unroll
        for (int j = 0; j < 4; ++j)
            acc[i][j] = (f32x4){0.f, 0.f, 0.f, 0.f};

    for (int kt = 0; kt < 32; ++kt) {
        const char* ga = abase + (kt << 14);
        const char* gb = bbase + (kt << 14);
        int toff = tid << 4;
        #pragma unroll
        for (int r = 0; r < 4; ++r) {
            gload_lds16(ga + (r << 12) + toff, smem + (r << 12) + toff);
            gload_lds16(gb + (r << 12) + toff, smem + 16384 + (r << 12) + toff);
        }
        __syncthreads();

        s16x8 ah[4], al[4], bh[4], bl[4];
        #pragma unroll
        for (int f = 0; f < 4; ++f) {
            ah[f] = *reinterpret_cast<const s16x8*>(smem + aoff_h[f]);
            al[f] = *reinterpret_cast<const s16x8*>(smem + aoff_l[f]);
            bh[f] = *reinterpret_cast<const s16x8*>(smem + boff_h[f]);
            bl[f] = *reinterpret_cast<const s16x8*>(smem + boff_l[f]);
        }
        #pragma unroll
        for (int m = 0; m < 4; ++m)
            #pragma unroll
            for (int n = 0; n < 4; ++n)
                acc[m][n] = MFMA_B16(ah[m], bh[n], acc[m][n], 0, 0, 0);
        #pragma unroll
        for (int m = 0; m < 4; ++m)
            #pragma unroll
            for (int n = 0; n < 4; ++n)
                acc[m][n] = MFMA_B16(ah[m], bl[n], acc[m][n], 0, 0, 0);
        #pragma unroll
        for (int m = 0; m < 4; ++m)
            #pragma unroll
            for (int n = 0; n < 4; ++n)
                acc[m][n] = MFMA_B16(al[m], bh[n], acc[m][n], 0, 0, 0);
        __syncthreads();
    }

    // ---- fused epilogue: P[row][e] = relu(acc + b1) @ W2slice, 3-pass split ----
    float bcol[4];
    #pragma unroll
    for (int fn = 0; fn < 4; ++fn) bcol[fn] = bias[col0g + wn + fn * 16 + l15];

    f32x4 plog[2];
    plog[0] = (f32x4){0.f, 0.f, 0.f, 0.f};
    plog[1] = (f32x4){0.f, 0.f, 0.f, 0.f};

    #pragma unroll
    for (int ch = 0; ch < 2; ++ch) {
        // waves owning col-half ch write h hi/lo (swizzled) into As/Bs region
        if ((wave & 1) == ch) {
            #pragma unroll
            for (int fm = 0; fm < 4; ++fm)
                #pragma unroll
                for (int r = 0; r < 4; ++r) {
                    int row = wm + fm * 16 + l4 * 4 + r;
                    int rx = (row & 7) << 4;
                    #pragma unroll
                    for (int fn = 0; fn < 4; ++fn) {
                        float hv = fmaxf(acc[fm][fn][r] + bcol[fn], 0.f);
                        unsigned short hh = f2bf(hv);
                        unsigned short hl = f2bf(hv - bf2f(hh));
                        int byteoff = row * 128 + ((((fn * 16 + l15) * 2)) ^ rx);
                        *reinterpret_cast<unsigned short*>(smem + byteoff) = hh;
                        *reinterpret_cast<unsigned short*>(smem + 16384 + byteoff) = hl;
                    }
                }
        }
        __syncthreads();

        // all waves: logits MFMA over this 64-col half (K chunks kc=0,1)
        #pragma unroll
        for (int fmm = 0; fmm < 2; ++fmm) {
            int rowb = wave * 32 + fmm * 16 + l15;
            int rx = (rowb & 7) << 4;
            int rowbase = rowb * 128;
            #pragma unroll
            for (int kc = 0; kc < 2; ++kc) {
                int co = kc * 64 + l4 * 16;
                s16x8 ahi = *reinterpret_cast<const s16x8*>(smem + rowbase + (co ^ rx));
                s16x8 alo = *reinterpret_cast<const s16x8*>(smem + 16384 + rowbase + (co ^ rx));
                int wb = W2T_OFS + ch * 128 + kc * 64 + l4 * 16;
                s16x8 whi = *reinterpret_cast<const s16x8*>(smem + wb + l15 * W2T_PITCH);
                s16x8 wlo = *reinterpret_cast<const s16x8*>(smem + wb + (l15 + 8) * W2T_PITCH);
                plog[fmm] = MFMA_B16(ahi, whi, plog[fmm], 0, 0, 0);
                plog[fmm] = MFMA_B16(ahi, wlo, plog[fmm], 0, 0, 0);
                plog[fmm] = MFMA_B16(alo, whi, plog[fmm], 0, 0, 0);
            }
        }
        __syncthreads();
    }

    // store partials: P rows = rb*128 + wave*32 + fmm*16 + l4*4 + r, expert = l15
    if (l15 < 8) {
        #pragma unroll
        for (int fmm = 0; fmm < 2; ++fmm) {
            int rowg = rb * 128 + wave * 32 + fmm * 16 + l4 * 4;
            #pragma unroll
            for (int r = 0; r < 4; ++r)
                Plog[((size_t)cb * 8192 + rowg + r) * E_NUM + l15] = plog[fmm][r];
        }
    }
}

// ---------------- combine: reduce partials -> softmax -> top2 -> gather ------
__global__ __launch_bounds__(256) void route_combine2_kernel(
    const float* __restrict__ Plog, const float* __restrict__ b2,
    const float* __restrict__ EO, float* __restrict__ Out, int M)
{
    const int t = blockIdx.x;
    const int tid = threadIdx.x;

    __shared__ float s_logit[E_NUM];
    __shared__ float s_g[2];
    __shared__ int   s_e[2];

    if (tid < 64) {
        int cbi = tid >> 3, e = tid & 7;
        float v = Plog[((size_t)cbi * M + t) * E_NUM + e];
        v += __shfl_xor(v, 8, 64);
        v += __shfl_xor(v, 16, 64);
        v += __shfl_xor(v, 32, 64);
        if (tid < 8) s_logit[tid] = v + b2[tid];
    }
    __syncthreads();

    if (tid == 0) {
        float logits[E_NUM];
        #pragma unroll
        for (int e = 0; e < E_NUM; ++e) logits[e] = s_logit[e];
        float m = logits[0];
        #pragma unroll
        for (int e = 1; e < E_NUM; ++e) m = fmaxf(m, logits[e]);
        float p[E_NUM], ssum = 0.f;
        #pragma unroll
        for (int e = 0; e < E_NUM; ++e) { p[e] = expf(logits[e] - m); ssum += p[e]; }
        float inv = 1.f / ssum;
        #pragma unroll
        for (int e = 0; e < E_NUM; ++e) p[e] *= inv;
        int e0 = 0;
        #pragma unroll
        for (int e = 1; e < E_NUM; ++e) if (p[e] > p[e0]) e0 = e;
        int e1 = (e0 == 0) ? 1 : 0;
        #pragma unroll
        for (int e = 0; e < E_NUM; ++e)
            if (e != e0 && e != e1 && p[e] > p[e1]) e1 = e;
        s_g[0] = p[e0]; s_g[1] = p[e1];
        s_e[0] = e0;    s_e[1] = e1;
    }
    __syncthreads();

    const float g0 = s_g[0], g1 = s_g[1];
    const size_t base0 = ((size_t)s_e[0] * M + t) * H_DIM;
    const size_t base1 = ((size_t)s_e[1] * M + t) * H_DIM;
    const int d = tid * 4;
    float4 x0 = *reinterpret_cast<const float4*>(&EO[base0 + d]);
    float4 x1 = *reinterpret_cast<const float4*>(&EO[base1 + d]);
    float4 o;
    o.x = g0 * x0.x + g1 * x1.x;
    o.y = g0 * x0.y + g1 * x1.y;
    o.z = g0 * x0.z + g1 * x1.z;
    o.w = g0 * x0.w + g1 * x1.w;
    *reinterpret_cast<float4*>(&Out[(size_t)t * H_DIM + d]) = o;
}

// ---------------- R1 fallback fp32 SGEMM + old combine (verified) ----------------
#define BM 128
#define BN 128
#define BK 16
#define PAD_LD 132

__global__ __launch_bounds__(256) void gemm1_relu_kernel(
    const float* __restrict__ A, const float* __restrict__ W,
    const float* __restrict__ bias, float* __restrict__ Hout,
    int M, int N, int K)
{
    __shared__ float As[BK][PAD_LD];
    __shared__ float Bs[BK][PAD_LD];
    const int tid = threadIdx.x;
    const int tx = tid & 15;
    const int ty = tid >> 4;
    const int row0 = blockIdx.y * BM;
    const int col0 = blockIdx.x * BN;
    float acc[8][8];
    #pragma unroll
    for (int i = 0; i < 8; ++i)
        #pragma unroll
        for (int j = 0; j < 8; ++j) acc[i][j] = 0.f;
    const int a_row = tid >> 2;
    const int a_k4  = (tid & 3) * 4;
    const int b_col4 = (tid & 31) * 4;
    const int b_kk   = tid >> 5;
    for (int k0 = 0; k0 < K; k0 += BK) {
        #pragma unroll
        for (int half = 0; half < 2; ++half) {
            int r = a_row + half * 64;
            float4 av = *reinterpret_cast<const float4*>(&A[(size_t)(row0 + r) * K + k0 + a_k4]);
            As[a_k4 + 0][r] = av.x; As[a_k4 + 1][r] = av.y;
            As[a_k4 + 2][r] = av.z; As[a_k4 + 3][r] = av.w;
        }
        #pragma unroll
        for (int half = 0; half < 2; ++half) {
            int kk = b_kk + half * 8;
            float4 bv = *reinterpret_cast<const float4*>(&W[(size_t)(k0 + kk) * N + col0 + b_col4]);
            *reinterpret_cast<float4*>(&Bs[kk][b_col4]) = bv;
        }
        __syncthreads();
        #pragma unroll
        for (int k = 0; k < BK; ++k) {
            float4 a0 = *reinterpret_cast<const float4*>(&As[k][ty * 8]);
            float4 a1 = *reinterpret_cast<const float4*>(&As[k][ty * 8 + 4]);
            float4 b0 = *reinterpret_cast<const float4*>(&Bs[k][tx * 8]);
            float4 b1 = *reinterpret_cast<const float4*>(&Bs[k][tx * 8 + 4]);
            float a[8] = {a0.x, a0.y, a0.z, a0.w, a1.x, a1.y, a1.z, a1.w};
            float b[8] = {b0.x, b0.y, b0.z, b0.w, b1.x, b1.y, b1.z, b1.w};
            #pragma unroll
            for (int i = 0; i < 8; ++i)
                #pragma unroll
                for (int j = 0; j < 8; ++j)
                    acc[i][j] = fmaf(a[i], b[j], acc[i][j]);
        }
        __syncthreads();
    }
    #pragma unroll
    for (int i = 0; i < 8; ++i) {
        int row = row0 + ty * 8 + i;
        #pragma unroll
        for (int j4 = 0; j4 < 2; ++j4) {
            int col = col0 + tx * 8 + j4 * 4;
            float4 v;
            v.x = fmaxf(acc[i][j4 * 4 + 0] + bias[col + 0], 0.f);
            v.y = fmaxf(acc[i][j4 * 4 + 1] + bias[col + 1], 0.f);
            v.z = fmaxf(acc[i][j4 * 4 + 2] + bias[col + 2], 0.f);
            v.w = fmaxf(acc[i][j4 * 4 + 3] + bias[col + 3], 0.f);
            *reinterpret_cast<float4*>(&Hout[(size_t)row * N + col]) = v;
        }
    }
}

__global__ __launch_bounds__(256) void route_combine_kernel(
    const float* __restrict__ Hbuf, const float* __restrict__ W2,
    const float* __restrict__ b2, const float* __restrict__ EO,
    float* __restrict__ Out, int M)
{
    const int t = blockIdx.x;
    const int tid = threadIdx.x;
    const int lane = tid & 63;
    const int wave = tid >> 6;
    const float* hrow = Hbuf + (size_t)t * H_DIM;

    float part[E_NUM];
    #pragma unroll
    for (int e = 0; e < E_NUM; ++e) part[e] = 0.f;
    #pragma unroll
    for (int it = 0; it < H_DIM / 256; ++it) {
        int j = tid + it * 256;
        float hv = hrow[j];
        const float* w = W2 + (size_t)j * E_NUM;
        #pragma unroll
        for (int e = 0; e < E_NUM; ++e) part[e] = fmaf(hv, w[e], part[e]);
    }
    #pragma unroll
    for (int off = 32; off > 0; off >>= 1)
        #pragma unroll
        for (int e = 0; e < E_NUM; ++e)
            part[e] += __shfl_down(part[e], off, 64);

    __shared__ float sred[4][E_NUM];
    __shared__ float s_g[2];
    __shared__ int   s_e[2];
    if (lane == 0)
        #pragma unroll
        for (int e = 0; e < E_NUM; ++e) sred[wave][e] = part[e];
    __syncthreads();

    if (tid == 0) {
        float logits[E_NUM];
        #pragma unroll
        for (int e = 0; e < E_NUM; ++e)
            logits[e] = sred[0][e] + sred[1][e] + sred[2][e] + sred[3][e] + b2[e];
        float m = logits[0];
        #pragma unroll
        for (int e = 1; e < E_NUM; ++e) m = fmaxf(m, logits[e]);
        float p[E_NUM], ssum = 0.f;
        #pragma unroll
        for (int e = 0; e < E_NUM; ++e) { p[e] = expf(logits[e] - m); ssum += p[e]; }
        float inv = 1.f / ssum;
        #pragma unroll
        for (int e = 0; e < E_NUM; ++e) p[e] *= inv;
        int e0 = 0;
        #pragma unroll
        for (int e = 1; e < E_NUM; ++e) if (p[e] > p[e0]) e0 = e;
        int e1 = (e0 == 0) ? 1 : 0;
        #pragma unroll
        for (int e = 0; e < E_NUM; ++e)
            if (e != e0 && e != e1 && p[e] > p[e1]) e1 = e;
        s_g[0] = p[e0]; s_g[1] = p[e1];
        s_e[0] = e0;    s_e[1] = e1;
    }
    __syncthreads();

    const float g0 = s_g[0], g1 = s_g[1];
    const size_t base0 = ((size_t)s_e[0] * M + t) * H_DIM;
    const size_t base1 = ((size_t)s_e[1] * M + t) * H_DIM;
    const int d = tid * 4;
    float4 x0 = *reinterpret_cast<const float4*>(&EO[base0 + d]);
    float4 x1 = *reinterpret_cast<const float4*>(&EO[base1 + d]);
    float4 o;
    o.x = g0 * x0.x + g1 * x1.x;
    o.y = g0 * x0.y + g1 * x1.y;
    o.z = g0 * x0.z + g1 * x1.z;
    o.w = g0 * x0.w + g1 * x1.w;
    *reinterpret_cast<float4*>(&Out[(size_t)t * H_DIM + d]) = o;
}

extern "C" void kernel_launch(void* const* d_in, const int* in_sizes, int n_in,
                              void* d_out, int out_size, void* d_ws, size_t ws_size,
                              hipStream_t stream)
{
    const float* hs = (const float*)d_in[0];
    const float* EO = (const float*)d_in[1];
    const float* W1 = (const float*)d_in[2];
    const float* b1 = (const float*)d_in[3];
    const float* W2 = (const float*)d_in[4];
    const float* b2 = (const float*)d_in[5];

    const int M = in_sizes[0] / H_DIM;   // 8192
    float* out = (float*)d_out;

    const size_t A_IMG = (size_t)64 * 32 * 16384;       // 33,554,432
    const size_t B_IMG = (size_t)8 * 32 * 16384;        //  4,194,304
    const size_t PART  = (size_t)8 * 8192 * 8 * 4;      //  2,097,152
    if (M == 8192 && ws_size >= A_IMG + B_IMG + PART) {
        char*  Aimg = (char*)d_ws;
        char*  Bimg = (char*)d_ws + A_IMG;
        float* Plog = (float*)((char*)d_ws + A_IMG + B_IMG);
        prep_fused_kernel<<<4096 + 512, 256, 0, stream>>>(hs, W1, Aimg, Bimg);
        gemm1_logits_kernel<<<512, 256, 0, stream>>>(Aimg, Bimg, b1, W2, Plog);
        route_combine2_kernel<<<M, 256, 0, stream>>>(Plog, b2, EO, out, M);
    } else {
        dim3 grid1(H_DIM / BN, M / BM);
        gemm1_relu_kernel<<<grid1, 256, 0, stream>>>(hs, W1, b1, out, M, H_DIM, H_DIM);
        route_combine_kernel<<<M, 256, 0, stream>>>(out, W2, b2, EO, out, M);
    }
}